// Round 6
// baseline (740.223 us; speedup 1.0000x reference)
//
#include <hip/hip_runtime.h>
#include <math.h>

#define N_USERS_C 100000
#define N_ITEMS_C 50000
#define N_NODES_C 150000
#define N_EDGES_C 2000000
#define N_ENTRIES_C 4000000
#define DIM_C 64
#define DECAY_C 1e-4f
#define BATCH_C 4096

#define SCAN_ELEMS 2048
#define SCAN_NB ((N_NODES_C + SCAN_ELEMS - 1) / SCAN_ELEMS)  // 74

#define TILE_EDGES 2048
#define NTILES ((N_EDGES_C + TILE_EDGES - 1) / TILE_EDGES)   // 977

// 512 entry-balanced buckets: 256 user buckets x 391 nodes, 256 item x 196.
#define UB_NODES 391
#define IB_NODES 196
#define NBUCK 512
#define B1_DEPTH 14

// ws layout (4-byte units): cnt[150016] | off[150032] | cur[150016] |
//   bsum[256] | acc[16] | cursB1[512] | entries[4M int2]
#define WS_CNT 0
#define WS_OFF 150016
#define WS_CUR 300048
#define WS_BSUM 450064
#define WS_ACC 450320
#define WS_CB1 450336
#define WS_ENT 450848   // even -> 8B aligned

// ENT1 staging lives in the tail of d_out (floats [30.4M, 38.4M) of 38.4M+1),
// consumed by part2 BEFORE gather/transform overwrite that region.
#define ENT1_FLOAT_OFF 30400000

// ---------------------------------------------------------------------------
// Kernel 1: per-node degree histogram
// ---------------------------------------------------------------------------
__global__ __launch_bounds__(256) void hist_kernel(
    const int* __restrict__ edge_row, const int* __restrict__ edge_col,
    int* __restrict__ cnt) {
  int e = blockIdx.x * blockDim.x + threadIdx.x;
  if (e >= N_EDGES_C) return;
  atomicAdd(&cnt[edge_row[e]], 1);
  atomicAdd(&cnt[N_USERS_C + edge_col[e]], 1);
}

// ---------------------------------------------------------------------------
// Kernel 2a/b/c: exclusive scan over 150k counts
// ---------------------------------------------------------------------------
__global__ __launch_bounds__(256) void scan1_kernel(
    const int* __restrict__ cnt, int* __restrict__ off, int* __restrict__ bsum) {
  __shared__ int ts[256];
  const int tid = threadIdx.x;
  const int base = blockIdx.x * SCAN_ELEMS + tid * 8;
  int v[8];
  int s = 0;
  #pragma unroll
  for (int i = 0; i < 8; ++i) {
    int idx = base + i;
    int c = (idx < N_NODES_C) ? cnt[idx] : 0;
    v[i] = s;
    s += c;
  }
  ts[tid] = s;
  __syncthreads();
  #pragma unroll
  for (int o = 1; o < 256; o <<= 1) {
    int y = (tid >= o) ? ts[tid - o] : 0;
    __syncthreads();
    ts[tid] += y;
    __syncthreads();
  }
  const int exclT = ts[tid] - s;
  #pragma unroll
  for (int i = 0; i < 8; ++i) {
    int idx = base + i;
    if (idx < N_NODES_C) off[idx] = exclT + v[i];
  }
  if (tid == 255) bsum[blockIdx.x] = ts[255];
}

__global__ void scan2_kernel(int* __restrict__ bsum) {
  if (threadIdx.x == 0 && blockIdx.x == 0) {
    int s = 0;
    for (int i = 0; i < SCAN_NB; ++i) {
      int t = bsum[i];
      bsum[i] = s;
      s += t;
    }
  }
}

__global__ __launch_bounds__(256) void scan3_kernel(
    int* __restrict__ off, int* __restrict__ cursor,
    const int* __restrict__ bsum) {
  const int base = blockIdx.x * SCAN_ELEMS + threadIdx.x * 8;
  const int add = bsum[blockIdx.x];
  #pragma unroll
  for (int i = 0; i < 8; ++i) {
    int idx = base + i;
    if (idx < N_NODES_C) {
      int o = off[idx] + add;
      off[idx] = o;
      cursor[idx] = o;
    }
  }
  if (blockIdx.x == 0 && threadIdx.x == 0) off[N_NODES_C] = N_ENTRIES_C;
}

// bucket cursor init: cursB1[b] = off[first node of bucket b]
__global__ void binit_kernel(const int* __restrict__ off,
                             int* __restrict__ cursB1) {
  int b = blockIdx.x * 256 + threadIdx.x;
  if (b >= NBUCK) return;
  int nb = (b < 256) ? b * UB_NODES : N_USERS_C + (b - 256) * IB_NODES;
  cursB1[b] = off[nb];
}

// ---------------------------------------------------------------------------
// Phase B1: bin entries into 512 buckets with LDS staging + chunked flush.
// Entry packing: x = src | (local_node << 17), y = val bits.
// ---------------------------------------------------------------------------
__global__ __launch_bounds__(256) void part1_kernel(
    const int* __restrict__ edge_row, const int* __restrict__ edge_col,
    const float* __restrict__ edge_val, int* __restrict__ cursB1,
    int2* __restrict__ ent1) {
  __shared__ int2 stg[NBUCK][B1_DEPTH];  // 56 KB
  __shared__ int scnt[NBUCK];            // 2 KB
  const int tid = threadIdx.x;
  for (int i = tid; i < NBUCK; i += 256) scnt[i] = 0;
  __syncthreads();

  const int base = blockIdx.x * TILE_EDGES;
  #pragma unroll
  for (int k = 0; k < 8; ++k) {
    int e = base + k * 256 + tid;
    if (e < N_EDGES_C) {
      int r = edge_row[e];
      int c = edge_col[e];
      int vb = __float_as_int(edge_val[e]);
      // user-destination entry
      int ub = (int)((unsigned)r / UB_NODES);
      int2 E1 = make_int2(c | ((r - ub * UB_NODES) << 17), vb);
      int s1 = atomicAdd(&scnt[ub], 1);
      if (s1 < B1_DEPTH) stg[ub][s1] = E1;
      else ent1[atomicAdd(&cursB1[ub], 1)] = E1;
      // item-destination entry
      int ib = (int)((unsigned)c / IB_NODES);
      int2 E2 = make_int2(r | ((c - ib * IB_NODES) << 17), vb);
      ib += 256;
      int s2 = atomicAdd(&scnt[ib], 1);
      if (s2 < B1_DEPTH) stg[ib][s2] = E2;
      else ent1[atomicAdd(&cursB1[ib], 1)] = E2;
    }
  }
  __syncthreads();
  for (int i = tid; i < NBUCK; i += 256) {
    int cn = scnt[i];
    if (cn > B1_DEPTH) cn = B1_DEPTH;
    if (cn) {
      int p = atomicAdd(&cursB1[i], cn);
      for (int j = 0; j < cn; ++j) ent1[p + j] = stg[i][j];
    }
  }
}

// ---------------------------------------------------------------------------
// Phase B2: exact CSR scatter within each bucket (writes span ~62 KB,
// time-local -> full-line writebacks).
// ---------------------------------------------------------------------------
__global__ __launch_bounds__(256) void part2_kernel(
    const int* __restrict__ off, const int2* __restrict__ ent1,
    int* __restrict__ cursor, int2* __restrict__ ent) {
  const int b = blockIdx.x;
  int nb, nbN;
  if (b < 256) {
    nb = b * UB_NODES;
    nbN = (b + 1) * UB_NODES;
    if (nbN > N_USERS_C) nbN = N_USERS_C;
  } else {
    nb = N_USERS_C + (b - 256) * IB_NODES;
    nbN = N_USERS_C + (b - 255) * IB_NODES;
    if (nbN > N_NODES_C) nbN = N_NODES_C;
  }
  const int start = off[nb];
  const int end = off[nbN];
  for (int i = start + threadIdx.x; i < end; i += 256) {
    int2 E = ent1[i];
    int node = nb + (int)((unsigned)E.x >> 17);
    int p = atomicAdd(&cursor[node], 1);
    ent[p] = make_int2(E.x & 0x1FFFF, E.y);
  }
}

// ---------------------------------------------------------------------------
// Gather (round-5 proven): streaming, quarter-wave per entry, 8 rows in
// flight per wave. Writes agg row into out's ego slot (scratch).
// ---------------------------------------------------------------------------
__global__ __launch_bounds__(256) void gather_kernel(
    const float* __restrict__ user_emb, const float* __restrict__ item_emb,
    const int* __restrict__ off, const int2* __restrict__ entries,
    float* __restrict__ out) {
  const int lane = threadIdx.x & 63;
  const int quarter = lane >> 4;
  const int ql = lane & 15;
  const int wave0 = (blockIdx.x * 256 + threadIdx.x) >> 6;
  const int nWaves = gridDim.x * 4;

  for (int n = wave0; n < N_NODES_C; n += nWaves) {
    const float* __restrict__ T = (n < N_USERS_C) ? item_emb : user_emb;
    int i = off[n] + quarter;
    const int end = off[n + 1];
    float4 acc = make_float4(0.f, 0.f, 0.f, 0.f);
    for (; i + 4 < end; i += 8) {
      int2 e0 = entries[i];
      int2 e1 = entries[i + 4];
      float4 r0 = *(const float4*)(T + ((size_t)e0.x << 6) + (ql << 2));
      float4 r1 = *(const float4*)(T + ((size_t)e1.x << 6) + (ql << 2));
      float v0 = __int_as_float(e0.y);
      float v1 = __int_as_float(e1.y);
      acc.x += v0 * r0.x + v1 * r1.x;
      acc.y += v0 * r0.y + v1 * r1.y;
      acc.z += v0 * r0.z + v1 * r1.z;
      acc.w += v0 * r0.w + v1 * r1.w;
    }
    if (i < end) {
      int2 e0 = entries[i];
      float4 r0 = *(const float4*)(T + ((size_t)e0.x << 6) + (ql << 2));
      float v0 = __int_as_float(e0.y);
      acc.x += v0 * r0.x;
      acc.y += v0 * r0.y;
      acc.z += v0 * r0.z;
      acc.w += v0 * r0.w;
    }
    acc.x += __shfl_xor(acc.x, 16); acc.x += __shfl_xor(acc.x, 32);
    acc.y += __shfl_xor(acc.y, 16); acc.y += __shfl_xor(acc.y, 32);
    acc.z += __shfl_xor(acc.z, 16); acc.z += __shfl_xor(acc.z, 32);
    acc.w += __shfl_xor(acc.w, 16); acc.w += __shfl_xor(acc.w, 32);
    if (lane < 16) *(float4*)&out[1 + (size_t)n * 256 + (ql << 2)] = acc;
  }
}

// ---------------------------------------------------------------------------
// Transform v2: lane = node. s[64] in VGPRs, W/b via uniform scalar loads,
// agg float4 re-loaded per k-chunk from the ego slot (L2-merged), no LDS,
// no shuffles (q is lane-local). Ego overwritten last.
// ---------------------------------------------------------------------------
__global__ __launch_bounds__(256) void transform_kernel(
    const float* __restrict__ user_emb, const float* __restrict__ item_emb,
    const float* __restrict__ W, const float* __restrict__ bvec,
    float* __restrict__ out) {
  const int n = blockIdx.x * 256 + threadIdx.x;
  if (n >= N_NODES_C) return;
  float* __restrict__ row = out + 1 + (size_t)n * 256;

  for (int l = 0; l < 3; ++l) {
    const float* __restrict__ bl = bvec + l * DIM_C;
    const float* __restrict__ Wl = W + l * DIM_C * DIM_C;
    float s[DIM_C];
    #pragma unroll
    for (int c = 0; c < DIM_C; ++c) s[c] = bl[c];  // uniform -> s_load

    #pragma unroll 1
    for (int kc = 0; kc < 16; ++kc) {
      const float4 a4 = *(const float4*)(row + kc * 4);
      const float* __restrict__ w0 = Wl + (kc * 4 + 0) * DIM_C;
      const float* __restrict__ w1 = Wl + (kc * 4 + 1) * DIM_C;
      const float* __restrict__ w2 = Wl + (kc * 4 + 2) * DIM_C;
      const float* __restrict__ w3 = Wl + (kc * 4 + 3) * DIM_C;
      #pragma unroll
      for (int c = 0; c < DIM_C; ++c)
        s[c] += a4.x * w0[c] + a4.y * w1[c] + a4.z * w2[c] + a4.w * w3[c];
    }

    float q = 0.f;
    #pragma unroll
    for (int c = 0; c < DIM_C; ++c) {
      s[c] = (s[c] >= 0.f) ? s[c] : 0.2f * s[c];
      q += s[c] * s[c];
    }
    const float rn = 1.0f / fmaxf(sqrtf(q), 1e-12f);
    #pragma unroll
    for (int c4 = 0; c4 < 16; ++c4) {
      float4 o;
      o.x = s[c4 * 4 + 0] * rn;
      o.y = s[c4 * 4 + 1] * rn;
      o.z = s[c4 * 4 + 2] * rn;
      o.w = s[c4 * 4 + 3] * rn;
      *(float4*)(row + (size_t)(l + 1) * 64 + c4 * 4) = o;
    }
  }

  // true ego overwrite (agg fully consumed above)
  const float* __restrict__ ego =
      (n < N_USERS_C) ? user_emb + (size_t)n * DIM_C
                      : item_emb + (size_t)(n - N_USERS_C) * DIM_C;
  #pragma unroll
  for (int c4 = 0; c4 < 16; ++c4)
    *(float4*)(row + c4 * 4) = *(const float4*)(ego + c4 * 4);
}

// ---------------------------------------------------------------------------
// Loss + finalize
// ---------------------------------------------------------------------------
__global__ __launch_bounds__(256) void loss_kernel(
    const float* __restrict__ out, const int* __restrict__ bu,
    const int* __restrict__ bp, const int* __restrict__ bn,
    float* __restrict__ acc) {
  const int wave = threadIdx.x >> 6;
  const int lane = threadIdx.x & 63;
  const int j = blockIdx.x * 4 + wave;
  if (j >= BATCH_C) return;

  const float* urow = out + 1 + (size_t)bu[j] * 256;
  const float* prow = out + 1 + ((size_t)N_USERS_C + bp[j]) * 256;
  const float* nrow = out + 1 + ((size_t)N_USERS_C + bn[j]) * 256;

  float4 u = ((const float4*)urow)[lane];
  float4 pp = ((const float4*)prow)[lane];
  float4 nn = ((const float4*)nrow)[lane];

  float x = u.x * (pp.x - nn.x) + u.y * (pp.y - nn.y) +
            u.z * (pp.z - nn.z) + u.w * (pp.w - nn.w);
  float r = u.x * u.x + u.y * u.y + u.z * u.z + u.w * u.w +
            pp.x * pp.x + pp.y * pp.y + pp.z * pp.z + pp.w * pp.w +
            nn.x * nn.x + nn.y * nn.y + nn.z * nn.z + nn.w * nn.w;

  #pragma unroll
  for (int o = 32; o; o >>= 1) {
    x += __shfl_xor(x, o);
    r += __shfl_xor(r, o);
  }
  if (lane == 0) {
    float ls = fminf(x, 0.f) - log1pf(expf(-fabsf(x)));
    atomicAdd(&acc[0], -ls);
    atomicAdd(&acc[1], 0.5f * r);
  }
}

__global__ void finalize_kernel(const float* __restrict__ acc,
                                float* __restrict__ out) {
  out[0] = acc[0] / (float)BATCH_C + DECAY_C * acc[1] / (float)BATCH_C;
}

// ---------------------------------------------------------------------------
extern "C" void kernel_launch(void* const* d_in, const int* in_sizes, int n_in,
                              void* d_out, int out_size, void* d_ws, size_t ws_size,
                              hipStream_t stream) {
  const float* user_emb = (const float*)d_in[0];
  const float* item_emb = (const float*)d_in[1];
  const float* edge_val = (const float*)d_in[2];
  const float* W        = (const float*)d_in[3];
  const float* bvec     = (const float*)d_in[4];
  const int* edge_row   = (const int*)d_in[5];
  const int* edge_col   = (const int*)d_in[6];
  const int* bu         = (const int*)d_in[7];
  const int* bp         = (const int*)d_in[8];
  const int* bn         = (const int*)d_in[9];

  float* out = (float*)d_out;
  int* ws = (int*)d_ws;
  int*  cnt    = ws + WS_CNT;
  int*  off    = ws + WS_OFF;
  int*  cursor = ws + WS_CUR;
  int*  bsum   = ws + WS_BSUM;
  float* acc   = (float*)(ws + WS_ACC);
  int*  cursB1 = ws + WS_CB1;
  int2* ent    = (int2*)(ws + WS_ENT);
  int2* ent1   = (int2*)(out + ENT1_FLOAT_OFF);  // d_out tail staging

  hipMemsetAsync(cnt, 0, 150016 * sizeof(int), stream);
  hipMemsetAsync(acc, 0, 2 * sizeof(float), stream);

  hist_kernel<<<(N_EDGES_C + 255) / 256, 256, 0, stream>>>(edge_row, edge_col, cnt);
  scan1_kernel<<<SCAN_NB, 256, 0, stream>>>(cnt, off, bsum);
  scan2_kernel<<<1, 64, 0, stream>>>(bsum);
  scan3_kernel<<<SCAN_NB, 256, 0, stream>>>(off, cursor, bsum);
  binit_kernel<<<2, 256, 0, stream>>>(off, cursB1);
  part1_kernel<<<NTILES, 256, 0, stream>>>(edge_row, edge_col, edge_val,
                                           cursB1, ent1);
  part2_kernel<<<NBUCK, 256, 0, stream>>>(off, ent1, cursor, ent);
  gather_kernel<<<2048, 256, 0, stream>>>(user_emb, item_emb, off, ent, out);
  transform_kernel<<<(N_NODES_C + 255) / 256, 256, 0, stream>>>(
      user_emb, item_emb, W, bvec, out);
  loss_kernel<<<BATCH_C / 4, 256, 0, stream>>>(out, bu, bp, bn, acc);
  finalize_kernel<<<1, 1, 0, stream>>>(acc, out);
}

// Round 7
// 633.697 us; speedup vs baseline: 1.1681x; 1.1681x over previous
//
#include <hip/hip_runtime.h>
#include <math.h>

#define N_USERS_C 100000
#define N_ITEMS_C 50000
#define N_NODES_C 150000
#define N_EDGES_C 2000000
#define N_ENTRIES_C 4000000
#define DIM_C 64
#define DECAY_C 1e-4f
#define BATCH_C 4096

#define SCAN_ELEMS 2048
#define SCAN_NB ((N_NODES_C + SCAN_ELEMS - 1) / SCAN_ELEMS)  // 74

#define TILE_EDGES 2048
#define NTILES ((N_EDGES_C + TILE_EDGES - 1) / TILE_EDGES)   // 977

// 512 entry-balanced buckets: 256 user buckets x 391 nodes, 256 item x 196.
#define UB_NODES 391
#define IB_NODES 196
#define NBUCK 512
#define B1_DEPTH 14

// ws layout (4-byte units):
//   off[150032] | cnt/cursor[150016] (shared) | bsum[256] | acc[16] |
//   cursB1[512] | entP[4M ints] | bf16 tables (9.6M halfs = 4.8M ints)
#define WS_OFF 0
#define WS_CUR 150032
#define WS_BSUM 300048
#define WS_ACC 300304
#define WS_CB1 300320
#define WS_ENT 300832
#define WS_BF16 4300832
// total 9,100,832 ints = 36.4 MB (ws proven >= 38.4 MB in round 1)

// ent1 staging (8B entries, f32 val) in d_out tail, consumed by part2
#define ENT1_FLOAT_OFF 30400000

__device__ __forceinline__ unsigned bf16_bits(float v) {
  unsigned u = __float_as_uint(v);
  return (u + 0x8000u) >> 16;  // round-to-nearest (no ties-to-even, fine)
}

// ---------------------------------------------------------------------------
// Kernel 0: cast both tables to bf16 (user table then item table, contiguous)
// ---------------------------------------------------------------------------
__global__ __launch_bounds__(256) void cast_kernel(
    const float* __restrict__ user_emb, const float* __restrict__ item_emb,
    ushort* __restrict__ h) {
  const int t = blockIdx.x * 256 + threadIdx.x;  // one float4 per thread
  const int nUser4 = N_USERS_C * DIM_C / 4;      // 1.6M
  const int nTot4 = (N_USERS_C + N_ITEMS_C) * DIM_C / 4;
  if (t >= nTot4) return;
  float4 v = (t < nUser4) ? ((const float4*)user_emb)[t]
                          : ((const float4*)item_emb)[t - nUser4];
  ushort4 o;
  o.x = (ushort)bf16_bits(v.x);
  o.y = (ushort)bf16_bits(v.y);
  o.z = (ushort)bf16_bits(v.z);
  o.w = (ushort)bf16_bits(v.w);
  *(ushort4*)&h[(size_t)t * 4] = o;
}

// ---------------------------------------------------------------------------
// Kernel 1: per-node degree histogram
// ---------------------------------------------------------------------------
__global__ __launch_bounds__(256) void hist_kernel(
    const int* __restrict__ edge_row, const int* __restrict__ edge_col,
    int* __restrict__ cnt) {
  int e = blockIdx.x * blockDim.x + threadIdx.x;
  if (e >= N_EDGES_C) return;
  atomicAdd(&cnt[edge_row[e]], 1);
  atomicAdd(&cnt[N_USERS_C + edge_col[e]], 1);
}

// ---------------------------------------------------------------------------
// Kernel 2a/b/c: exclusive scan over 150k counts
// ---------------------------------------------------------------------------
__global__ __launch_bounds__(256) void scan1_kernel(
    const int* __restrict__ cnt, int* __restrict__ off, int* __restrict__ bsum) {
  __shared__ int ts[256];
  const int tid = threadIdx.x;
  const int base = blockIdx.x * SCAN_ELEMS + tid * 8;
  int v[8];
  int s = 0;
  #pragma unroll
  for (int i = 0; i < 8; ++i) {
    int idx = base + i;
    int c = (idx < N_NODES_C) ? cnt[idx] : 0;
    v[i] = s;
    s += c;
  }
  ts[tid] = s;
  __syncthreads();
  #pragma unroll
  for (int o = 1; o < 256; o <<= 1) {
    int y = (tid >= o) ? ts[tid - o] : 0;
    __syncthreads();
    ts[tid] += y;
    __syncthreads();
  }
  const int exclT = ts[tid] - s;
  #pragma unroll
  for (int i = 0; i < 8; ++i) {
    int idx = base + i;
    if (idx < N_NODES_C) off[idx] = exclT + v[i];
  }
  if (tid == 255) bsum[blockIdx.x] = ts[255];
}

__global__ void scan2_kernel(int* __restrict__ bsum) {
  if (threadIdx.x == 0 && blockIdx.x == 0) {
    int s = 0;
    for (int i = 0; i < SCAN_NB; ++i) {
      int t = bsum[i];
      bsum[i] = s;
      s += t;
    }
  }
}

__global__ __launch_bounds__(256) void scan3_kernel(
    int* __restrict__ off, int* __restrict__ cursor,
    const int* __restrict__ bsum) {
  const int base = blockIdx.x * SCAN_ELEMS + threadIdx.x * 8;
  const int add = bsum[blockIdx.x];
  #pragma unroll
  for (int i = 0; i < 8; ++i) {
    int idx = base + i;
    if (idx < N_NODES_C) {
      int o = off[idx] + add;
      off[idx] = o;
      cursor[idx] = o;
    }
  }
  if (blockIdx.x == 0 && threadIdx.x == 0) off[N_NODES_C] = N_ENTRIES_C;
}

__global__ void binit_kernel(const int* __restrict__ off,
                             int* __restrict__ cursB1) {
  int b = blockIdx.x * 256 + threadIdx.x;
  if (b >= NBUCK) return;
  int nb = (b < 256) ? b * UB_NODES : N_USERS_C + (b - 256) * IB_NODES;
  cursB1[b] = off[nb];
}

// ---------------------------------------------------------------------------
// Phase B1: bin entries into 512 buckets (LDS staging + chunked flush).
// ent1 packing: x = src | (local_node << 17), y = f32 val bits.
// ---------------------------------------------------------------------------
__global__ __launch_bounds__(256) void part1_kernel(
    const int* __restrict__ edge_row, const int* __restrict__ edge_col,
    const float* __restrict__ edge_val, int* __restrict__ cursB1,
    int2* __restrict__ ent1) {
  __shared__ int2 stg[NBUCK][B1_DEPTH];  // 56 KB
  __shared__ int scnt[NBUCK];
  const int tid = threadIdx.x;
  for (int i = tid; i < NBUCK; i += 256) scnt[i] = 0;
  __syncthreads();

  const int base = blockIdx.x * TILE_EDGES;
  #pragma unroll
  for (int k = 0; k < 8; ++k) {
    int e = base + k * 256 + tid;
    if (e < N_EDGES_C) {
      int r = edge_row[e];
      int c = edge_col[e];
      int vb = __float_as_int(edge_val[e]);
      int ub = (int)((unsigned)r / UB_NODES);
      int2 E1 = make_int2(c | ((r - ub * UB_NODES) << 17), vb);
      int s1 = atomicAdd(&scnt[ub], 1);
      if (s1 < B1_DEPTH) stg[ub][s1] = E1;
      else ent1[atomicAdd(&cursB1[ub], 1)] = E1;
      int ib = (int)((unsigned)c / IB_NODES);
      int2 E2 = make_int2(r | ((c - ib * IB_NODES) << 17), vb);
      ib += 256;
      int s2 = atomicAdd(&scnt[ib], 1);
      if (s2 < B1_DEPTH) stg[ib][s2] = E2;
      else ent1[atomicAdd(&cursB1[ib], 1)] = E2;
    }
  }
  __syncthreads();
  for (int i = tid; i < NBUCK; i += 256) {
    int cn = scnt[i];
    if (cn > B1_DEPTH) cn = B1_DEPTH;
    if (cn) {
      int p = atomicAdd(&cursB1[i], cn);
      for (int j = 0; j < cn; ++j) ent1[p + j] = stg[i][j];
    }
  }
}

// ---------------------------------------------------------------------------
// Phase B2: exact CSR scatter within each bucket -> packed 4B entries.
// user-dest: P = (bf16(val)<<16) | src16
// item-dest: P = ((bf16(val)&0xFFFE | src&1)<<16) | (src>>1)
// ---------------------------------------------------------------------------
__global__ __launch_bounds__(256) void part2_kernel(
    const int* __restrict__ off, const int2* __restrict__ ent1,
    int* __restrict__ cursor, unsigned* __restrict__ entP) {
  const int b = blockIdx.x;
  int nb, nbN;
  if (b < 256) {
    nb = b * UB_NODES;
    nbN = (b + 1) * UB_NODES;
    if (nbN > N_USERS_C) nbN = N_USERS_C;
  } else {
    nb = N_USERS_C + (b - 256) * IB_NODES;
    nbN = N_USERS_C + (b - 255) * IB_NODES;
    if (nbN > N_NODES_C) nbN = N_NODES_C;
  }
  const int start = off[nb];
  const int end = off[nbN];
  const bool isUser = (b < 256);
  for (int i = start + threadIdx.x; i < end; i += 256) {
    int2 E = ent1[i];
    int node = nb + (int)((unsigned)E.x >> 17);
    int src = E.x & 0x1FFFF;
    unsigned hb = bf16_bits(__int_as_float(E.y));
    unsigned P;
    if (isUser) {
      P = (hb << 16) | (unsigned)src;
    } else {
      P = (((hb & 0xFFFEu) | ((unsigned)src & 1u)) << 16) |
          ((unsigned)src >> 1);
    }
    int p = atomicAdd(&cursor[node], 1);
    entP[p] = P;
  }
}

// ---------------------------------------------------------------------------
// Gather: streaming, quarter-wave (16 lanes x 8B bf16x4) per entry,
// 4 entries in flight per quarter -> 16 rows in flight per wave.
// Writes agg row into out's ego slot (scratch for transform).
// ---------------------------------------------------------------------------
__device__ __forceinline__ void acc_row(float4& acc, unsigned E, bool isUser,
                                        const ushort* __restrict__ tblU,
                                        const ushort* __restrict__ tblI,
                                        int ql) {
  unsigned src;
  float v;
  const ushort* t;
  if (isUser) {  // uniform branch per node
    src = E & 0xFFFFu;
    v = __uint_as_float(E & 0xFFFF0000u);
    t = tblI;
  } else {
    src = ((E & 0xFFFFu) << 1) | ((E >> 16) & 1u);
    v = __uint_as_float(E & 0xFFFE0000u);
    t = tblU;
  }
  uint2 q = *(const uint2*)(t + ((size_t)src << 6) + (ql << 2));
  acc.x += v * __uint_as_float(q.x << 16);
  acc.y += v * __uint_as_float(q.x & 0xFFFF0000u);
  acc.z += v * __uint_as_float(q.y << 16);
  acc.w += v * __uint_as_float(q.y & 0xFFFF0000u);
}

__global__ __launch_bounds__(256) void gather_kernel(
    const ushort* __restrict__ bf16tab, const int* __restrict__ off,
    const unsigned* __restrict__ entP, float* __restrict__ out) {
  const int lane = threadIdx.x & 63;
  const int quarter = lane >> 4;
  const int ql = lane & 15;
  const int wave0 = (blockIdx.x * 256 + threadIdx.x) >> 6;
  const int nWaves = gridDim.x * 4;
  const ushort* tblU = bf16tab;
  const ushort* tblI = bf16tab + (size_t)N_USERS_C * DIM_C;

  for (int n = wave0; n < N_NODES_C; n += nWaves) {
    const bool isUser = (n < N_USERS_C);
    int i = off[n] + quarter;
    const int end = off[n + 1];
    float4 acc = make_float4(0.f, 0.f, 0.f, 0.f);
    for (; i + 12 < end; i += 16) {
      unsigned e0 = entP[i];
      unsigned e1 = entP[i + 4];
      unsigned e2 = entP[i + 8];
      unsigned e3 = entP[i + 12];
      acc_row(acc, e0, isUser, tblU, tblI, ql);
      acc_row(acc, e1, isUser, tblU, tblI, ql);
      acc_row(acc, e2, isUser, tblU, tblI, ql);
      acc_row(acc, e3, isUser, tblU, tblI, ql);
    }
    for (; i < end; i += 4) {
      unsigned e0 = entP[i];
      acc_row(acc, e0, isUser, tblU, tblI, ql);
    }
    acc.x += __shfl_xor(acc.x, 16); acc.x += __shfl_xor(acc.x, 32);
    acc.y += __shfl_xor(acc.y, 16); acc.y += __shfl_xor(acc.y, 32);
    acc.z += __shfl_xor(acc.z, 16); acc.z += __shfl_xor(acc.z, 32);
    acc.w += __shfl_xor(acc.w, 16); acc.w += __shfl_xor(acc.w, 32);
    if (lane < 16) *(float4*)&out[1 + (size_t)n * 256 + (ql << 2)] = acc;
  }
}

// ---------------------------------------------------------------------------
// Transform (round-4 proven design): block = 32 nodes (8/wave), W staged
// per layer in LDS, agg staged from ego slots, coalesced access throughout.
// ---------------------------------------------------------------------------
__global__ __launch_bounds__(256) void transform_kernel(
    const float* __restrict__ user_emb, const float* __restrict__ item_emb,
    const float* __restrict__ W, const float* __restrict__ bvec,
    float* __restrict__ out) {
  __shared__ float Wl[DIM_C * DIM_C];  // 16 KB
  __shared__ float aggS[32][DIM_C];    // 8 KB
  const int tid = threadIdx.x;
  const int wave = tid >> 6;
  const int lane = tid & 63;
  const int n0 = blockIdx.x * 32;

  for (int k = tid; k < 512; k += 256) {
    int row = k >> 4;
    int c4 = k & 15;
    int n = n0 + row;
    float4 a = make_float4(0.f, 0.f, 0.f, 0.f);
    if (n < N_NODES_C) a = *(const float4*)&out[1 + (size_t)n * 256 + c4 * 4];
    *(float4*)&aggS[row][c4 * 4] = a;
  }
  __syncthreads();

  #pragma unroll
  for (int j = 0; j < 8; ++j) {
    int n = n0 + wave * 8 + j;
    if (n < N_NODES_C) {
      float e = (n < N_USERS_C) ? user_emb[(size_t)n * DIM_C + lane]
                                : item_emb[(size_t)(n - N_USERS_C) * DIM_C + lane];
      __builtin_nontemporal_store(e, &out[1 + (size_t)n * 256 + lane]);
    }
  }

  for (int l = 0; l < 3; ++l) {
    __syncthreads();
    {
      const float4* Wg = (const float4*)(W + l * DIM_C * DIM_C);
      float4* Wd = (float4*)Wl;
      #pragma unroll
      for (int i = 0; i < 4; ++i) Wd[tid + i * 256] = Wg[tid + i * 256];
    }
    __syncthreads();

    const float bias = bvec[l * DIM_C + lane];
    float acc[8];
    #pragma unroll
    for (int j = 0; j < 8; ++j) acc[j] = bias;

    #pragma unroll 4
    for (int k4 = 0; k4 < 16; ++k4) {
      const float w0 = Wl[(k4 * 4 + 0) * DIM_C + lane];
      const float w1 = Wl[(k4 * 4 + 1) * DIM_C + lane];
      const float w2 = Wl[(k4 * 4 + 2) * DIM_C + lane];
      const float w3 = Wl[(k4 * 4 + 3) * DIM_C + lane];
      #pragma unroll
      for (int j = 0; j < 8; ++j) {
        const float4 a = *(const float4*)&aggS[wave * 8 + j][k4 * 4];
        acc[j] += a.x * w0 + a.y * w1 + a.z * w2 + a.w * w3;
      }
    }

    #pragma unroll
    for (int j = 0; j < 8; ++j) {
      int n = n0 + wave * 8 + j;
      float s = acc[j];
      s = (s >= 0.f) ? s : 0.2f * s;
      float q = s * s;
      #pragma unroll
      for (int o = 32; o; o >>= 1) q += __shfl_xor(q, o);
      if (n < N_NODES_C) {
        float val = s / fmaxf(sqrtf(q), 1e-12f);
        __builtin_nontemporal_store(
            val, &out[1 + (size_t)n * 256 + (size_t)(l + 1) * 64 + lane]);
      }
    }
  }
}

// ---------------------------------------------------------------------------
// Loss + finalize
// ---------------------------------------------------------------------------
__global__ __launch_bounds__(256) void loss_kernel(
    const float* __restrict__ out, const int* __restrict__ bu,
    const int* __restrict__ bp, const int* __restrict__ bn,
    float* __restrict__ acc) {
  const int wave = threadIdx.x >> 6;
  const int lane = threadIdx.x & 63;
  const int j = blockIdx.x * 4 + wave;
  if (j >= BATCH_C) return;

  const float* urow = out + 1 + (size_t)bu[j] * 256;
  const float* prow = out + 1 + ((size_t)N_USERS_C + bp[j]) * 256;
  const float* nrow = out + 1 + ((size_t)N_USERS_C + bn[j]) * 256;

  float4 u = ((const float4*)urow)[lane];
  float4 pp = ((const float4*)prow)[lane];
  float4 nn = ((const float4*)nrow)[lane];

  float x = u.x * (pp.x - nn.x) + u.y * (pp.y - nn.y) +
            u.z * (pp.z - nn.z) + u.w * (pp.w - nn.w);
  float r = u.x * u.x + u.y * u.y + u.z * u.z + u.w * u.w +
            pp.x * pp.x + pp.y * pp.y + pp.z * pp.z + pp.w * pp.w +
            nn.x * nn.x + nn.y * nn.y + nn.z * nn.z + nn.w * nn.w;

  #pragma unroll
  for (int o = 32; o; o >>= 1) {
    x += __shfl_xor(x, o);
    r += __shfl_xor(r, o);
  }
  if (lane == 0) {
    float ls = fminf(x, 0.f) - log1pf(expf(-fabsf(x)));
    atomicAdd(&acc[0], -ls);
    atomicAdd(&acc[1], 0.5f * r);
  }
}

__global__ void finalize_kernel(const float* __restrict__ acc,
                                float* __restrict__ out) {
  out[0] = acc[0] / (float)BATCH_C + DECAY_C * acc[1] / (float)BATCH_C;
}

// ---------------------------------------------------------------------------
extern "C" void kernel_launch(void* const* d_in, const int* in_sizes, int n_in,
                              void* d_out, int out_size, void* d_ws, size_t ws_size,
                              hipStream_t stream) {
  const float* user_emb = (const float*)d_in[0];
  const float* item_emb = (const float*)d_in[1];
  const float* edge_val = (const float*)d_in[2];
  const float* W        = (const float*)d_in[3];
  const float* bvec     = (const float*)d_in[4];
  const int* edge_row   = (const int*)d_in[5];
  const int* edge_col   = (const int*)d_in[6];
  const int* bu         = (const int*)d_in[7];
  const int* bp         = (const int*)d_in[8];
  const int* bn         = (const int*)d_in[9];

  float* out = (float*)d_out;
  int* ws = (int*)d_ws;
  int*  off    = ws + WS_OFF;
  int*  cursor = ws + WS_CUR;   // doubles as cnt (hist) before scan3
  int*  bsum   = ws + WS_BSUM;
  float* acc   = (float*)(ws + WS_ACC);
  int*  cursB1 = ws + WS_CB1;
  unsigned* entP = (unsigned*)(ws + WS_ENT);
  ushort* bf16tab = (ushort*)(ws + WS_BF16);
  int2* ent1 = (int2*)(out + ENT1_FLOAT_OFF);

  hipMemsetAsync(cursor, 0, 150016 * sizeof(int), stream);
  hipMemsetAsync(acc, 0, 2 * sizeof(float), stream);

  cast_kernel<<<(2400000 + 255) / 256, 256, 0, stream>>>(user_emb, item_emb,
                                                         bf16tab);
  hist_kernel<<<(N_EDGES_C + 255) / 256, 256, 0, stream>>>(edge_row, edge_col,
                                                           cursor);
  scan1_kernel<<<SCAN_NB, 256, 0, stream>>>(cursor, off, bsum);
  scan2_kernel<<<1, 64, 0, stream>>>(bsum);
  scan3_kernel<<<SCAN_NB, 256, 0, stream>>>(off, cursor, bsum);
  binit_kernel<<<2, 256, 0, stream>>>(off, cursB1);
  part1_kernel<<<NTILES, 256, 0, stream>>>(edge_row, edge_col, edge_val,
                                           cursB1, ent1);
  part2_kernel<<<NBUCK, 256, 0, stream>>>(off, ent1, cursor, entP);
  gather_kernel<<<2048, 256, 0, stream>>>(bf16tab, off, entP, out);
  transform_kernel<<<(N_NODES_C + 31) / 32, 256, 0, stream>>>(
      user_emb, item_emb, W, bvec, out);
  loss_kernel<<<BATCH_C / 4, 256, 0, stream>>>(out, bu, bp, bn, acc);
  finalize_kernel<<<1, 1, 0, stream>>>(acc, out);
}

// Round 8
// 481.041 us; speedup vs baseline: 1.5388x; 1.3173x over previous
//
#include <hip/hip_runtime.h>
#include <math.h>

#define N_USERS_C 100000
#define N_ITEMS_C 50000
#define N_NODES_C 150000
#define N_EDGES_C 2000000
#define N_ENTRIES_C 4000000
#define DIM_C 64
#define DECAY_C 1e-4f
#define BATCH_C 4096

#define TILE_EDGES 2048
#define NTILES ((N_EDGES_C + TILE_EDGES - 1) / TILE_EDGES)   // 977

// 512 entry-balanced buckets: 256 user buckets x 391 nodes, 256 item x 196.
#define UB_NODES 391
#define IB_NODES 196
#define NBUCK 512
#define B1_DEPTH 14

// ws layout (4-byte units):
//   off[150032] | bcnt[512] | bucketStart[520] | cursB1[512] | acc[24] |
//   entP[4M ints] | bf16 tables (9.6M halfs = 4.8M ints)
#define WS_OFF 0
#define WS_BCNT 150032
#define WS_BSTART 150544
#define WS_CB1 151064
#define WS_ACC 151576
#define WS_ENT 151600
#define WS_BF16 4151600
// total 8,951,600 ints = 35.8 MB

// ent1 staging (8B entries, f32 val) in d_out tail, consumed by part2
// before gather/transform overwrite that region (stream-ordered).
#define ENT1_FLOAT_OFF 30400000

__device__ __forceinline__ unsigned bf16_bits(float v) {
  unsigned u = __float_as_uint(v);
  return (u + 0x8000u) >> 16;
}

// ---------------------------------------------------------------------------
// Kernel 0: cast both tables to bf16 (user table then item table, contiguous)
// ---------------------------------------------------------------------------
__global__ __launch_bounds__(256) void cast_kernel(
    const float* __restrict__ user_emb, const float* __restrict__ item_emb,
    ushort* __restrict__ h) {
  const int t = blockIdx.x * 256 + threadIdx.x;  // one float4 per thread
  const int nUser4 = N_USERS_C * DIM_C / 4;
  const int nTot4 = (N_USERS_C + N_ITEMS_C) * DIM_C / 4;
  if (t >= nTot4) return;
  float4 v = (t < nUser4) ? ((const float4*)user_emb)[t]
                          : ((const float4*)item_emb)[t - nUser4];
  ushort4 o;
  o.x = (ushort)bf16_bits(v.x);
  o.y = (ushort)bf16_bits(v.y);
  o.z = (ushort)bf16_bits(v.z);
  o.w = (ushort)bf16_bits(v.w);
  *(ushort4*)&h[(size_t)t * 4] = o;
}

// ---------------------------------------------------------------------------
// Kernel 1: bucket-level histogram (512 bins, LDS-aggregated)
// ---------------------------------------------------------------------------
__global__ __launch_bounds__(256) void bucket_hist_kernel(
    const int* __restrict__ edge_row, const int* __restrict__ edge_col,
    int* __restrict__ bcnt) {
  __shared__ int h[NBUCK];
  const int tid = threadIdx.x;
  for (int i = tid; i < NBUCK; i += 256) h[i] = 0;
  __syncthreads();
  const int base = blockIdx.x * TILE_EDGES;
  #pragma unroll
  for (int k = 0; k < 8; ++k) {
    int e = base + k * 256 + tid;
    if (e < N_EDGES_C) {
      atomicAdd(&h[(int)((unsigned)edge_row[e] / UB_NODES)], 1);
      atomicAdd(&h[256 + (int)((unsigned)edge_col[e] / IB_NODES)], 1);
    }
  }
  __syncthreads();
  for (int i = tid; i < NBUCK; i += 256) {
    int v = h[i];
    if (v) atomicAdd(&bcnt[i], v);
  }
}

// ---------------------------------------------------------------------------
// Kernel 2: exclusive scan of 512 bucket counts (single block)
// ---------------------------------------------------------------------------
__global__ __launch_bounds__(512) void scan512_kernel(
    const int* __restrict__ bcnt, int* __restrict__ bucketStart,
    int* __restrict__ cursB1) {
  __shared__ int ts[512];
  const int t = threadIdx.x;
  int c = bcnt[t];
  ts[t] = c;
  __syncthreads();
  #pragma unroll
  for (int o = 1; o < 512; o <<= 1) {
    int y = (t >= o) ? ts[t - o] : 0;
    __syncthreads();
    ts[t] += y;
    __syncthreads();
  }
  int excl = ts[t] - c;
  bucketStart[t] = excl;
  cursB1[t] = excl;
  if (t == 511) bucketStart[512] = ts[511];
}

// ---------------------------------------------------------------------------
// Phase B1: bin entries into 512 buckets (LDS staging + chunked flush).
// ent1 packing: x = src | (local_node << 17), y = f32 val bits.
// ---------------------------------------------------------------------------
__global__ __launch_bounds__(256) void part1_kernel(
    const int* __restrict__ edge_row, const int* __restrict__ edge_col,
    const float* __restrict__ edge_val, int* __restrict__ cursB1,
    int2* __restrict__ ent1) {
  __shared__ int2 stg[NBUCK][B1_DEPTH];  // 56 KB
  __shared__ int scnt[NBUCK];
  const int tid = threadIdx.x;
  for (int i = tid; i < NBUCK; i += 256) scnt[i] = 0;
  __syncthreads();

  const int base = blockIdx.x * TILE_EDGES;
  #pragma unroll
  for (int k = 0; k < 8; ++k) {
    int e = base + k * 256 + tid;
    if (e < N_EDGES_C) {
      int r = edge_row[e];
      int c = edge_col[e];
      int vb = __float_as_int(edge_val[e]);
      int ub = (int)((unsigned)r / UB_NODES);
      int2 E1 = make_int2(c | ((r - ub * UB_NODES) << 17), vb);
      int s1 = atomicAdd(&scnt[ub], 1);
      if (s1 < B1_DEPTH) stg[ub][s1] = E1;
      else ent1[atomicAdd(&cursB1[ub], 1)] = E1;
      int ib = (int)((unsigned)c / IB_NODES);
      int2 E2 = make_int2(r | ((c - ib * IB_NODES) << 17), vb);
      ib += 256;
      int s2 = atomicAdd(&scnt[ib], 1);
      if (s2 < B1_DEPTH) stg[ib][s2] = E2;
      else ent1[atomicAdd(&cursB1[ib], 1)] = E2;
    }
  }
  __syncthreads();
  for (int i = tid; i < NBUCK; i += 256) {
    int cn = scnt[i];
    if (cn > B1_DEPTH) cn = B1_DEPTH;
    if (cn) {
      int p = atomicAdd(&cursB1[i], cn);
      for (int j = 0; j < cn; ++j) ent1[p + j] = stg[i][j];
    }
  }
}

// ---------------------------------------------------------------------------
// Phase B2: per-bucket local node histogram + LDS scan -> writes off[]
// coalesced, then scatters packed 4B entries via LDS cursor atomics.
// user-dest: P = (bf16(val)<<16) | src16
// item-dest: P = ((bf16(val)&0xFFFE | src&1)<<16) | (src>>1)
// ---------------------------------------------------------------------------
__global__ __launch_bounds__(256) void part2_kernel(
    const int* __restrict__ bucketStart, const int2* __restrict__ ent1,
    int* __restrict__ off, unsigned* __restrict__ entP) {
  __shared__ int lhist[512];
  __shared__ int lexcl[512];
  __shared__ int ps[256];
  const int b = blockIdx.x;
  const int tid = threadIdx.x;
  int nb, nodes;
  if (b < 256) {
    nb = b * UB_NODES;
    int e = (b + 1) * UB_NODES;
    if (e > N_USERS_C) e = N_USERS_C;
    nodes = e - nb;
  } else {
    nb = N_USERS_C + (b - 256) * IB_NODES;
    int e = N_USERS_C + (b - 255) * IB_NODES;
    if (e > N_NODES_C) e = N_NODES_C;
    nodes = e - nb;
  }
  const int start = bucketStart[b];
  const int end = bucketStart[b + 1];

  for (int i = tid; i < 512; i += 256) lhist[i] = 0;
  __syncthreads();

  // pass 1: local degree histogram
  for (int i = start + tid; i < end; i += 256)
    atomicAdd(&lhist[(unsigned)ent1[i].x >> 17], 1);
  __syncthreads();

  // exclusive scan of lhist[0..511] (2 elems/thread + HS over 256)
  int a0 = lhist[2 * tid];
  int a1 = lhist[2 * tid + 1];
  ps[tid] = a0 + a1;
  __syncthreads();
  #pragma unroll
  for (int o = 1; o < 256; o <<= 1) {
    int y = (tid >= o) ? ps[tid - o] : 0;
    __syncthreads();
    ps[tid] += y;
    __syncthreads();
  }
  int e0 = ps[tid] - a0 - a1;
  lexcl[2 * tid] = e0;
  lexcl[2 * tid + 1] = e0 + a0;
  __syncthreads();

  // write per-node CSR offsets (coalesced)
  for (int t = tid; t < nodes; t += 256) off[nb + t] = start + lexcl[t];
  if (b == NBUCK - 1 && tid == 0) off[N_NODES_C] = N_ENTRIES_C;

  // reset cursors = local offsets
  for (int i = tid; i < 512; i += 256) lhist[i] = lexcl[i];
  __syncthreads();

  // pass 2: scatter packed entries (span is L2-hot from pass 1)
  const bool isUser = (b < 256);
  for (int i = start + tid; i < end; i += 256) {
    int2 E = ent1[i];
    int local = (int)((unsigned)E.x >> 17);
    int src = E.x & 0x1FFFF;
    unsigned hb = bf16_bits(__int_as_float(E.y));
    unsigned P;
    if (isUser) {
      P = (hb << 16) | (unsigned)src;
    } else {
      P = (((hb & 0xFFFEu) | ((unsigned)src & 1u)) << 16) |
          ((unsigned)src >> 1);
    }
    int p = start + atomicAdd(&lhist[local], 1);
    entP[p] = P;
  }
}

// ---------------------------------------------------------------------------
// Gather: streaming, quarter-wave (16 lanes x 8B bf16x4) per entry,
// 4 entries in flight per quarter -> 16 rows in flight per wave.
// ---------------------------------------------------------------------------
__device__ __forceinline__ void acc_row(float4& acc, unsigned E, bool isUser,
                                        const ushort* __restrict__ tblU,
                                        const ushort* __restrict__ tblI,
                                        int ql) {
  unsigned src;
  float v;
  const ushort* t;
  if (isUser) {
    src = E & 0xFFFFu;
    v = __uint_as_float(E & 0xFFFF0000u);
    t = tblI;
  } else {
    src = ((E & 0xFFFFu) << 1) | ((E >> 16) & 1u);
    v = __uint_as_float(E & 0xFFFE0000u);
    t = tblU;
  }
  uint2 q = *(const uint2*)(t + ((size_t)src << 6) + (ql << 2));
  acc.x += v * __uint_as_float(q.x << 16);
  acc.y += v * __uint_as_float(q.x & 0xFFFF0000u);
  acc.z += v * __uint_as_float(q.y << 16);
  acc.w += v * __uint_as_float(q.y & 0xFFFF0000u);
}

__global__ __launch_bounds__(256) void gather_kernel(
    const ushort* __restrict__ bf16tab, const int* __restrict__ off,
    const unsigned* __restrict__ entP, float* __restrict__ out) {
  const int lane = threadIdx.x & 63;
  const int quarter = lane >> 4;
  const int ql = lane & 15;
  const int wave0 = (blockIdx.x * 256 + threadIdx.x) >> 6;
  const int nWaves = gridDim.x * 4;
  const ushort* tblU = bf16tab;
  const ushort* tblI = bf16tab + (size_t)N_USERS_C * DIM_C;

  for (int n = wave0; n < N_NODES_C; n += nWaves) {
    const bool isUser = (n < N_USERS_C);
    int i = off[n] + quarter;
    const int end = off[n + 1];
    float4 acc = make_float4(0.f, 0.f, 0.f, 0.f);
    for (; i + 12 < end; i += 16) {
      unsigned e0 = entP[i];
      unsigned e1 = entP[i + 4];
      unsigned e2 = entP[i + 8];
      unsigned e3 = entP[i + 12];
      acc_row(acc, e0, isUser, tblU, tblI, ql);
      acc_row(acc, e1, isUser, tblU, tblI, ql);
      acc_row(acc, e2, isUser, tblU, tblI, ql);
      acc_row(acc, e3, isUser, tblU, tblI, ql);
    }
    for (; i < end; i += 4) {
      unsigned e0 = entP[i];
      acc_row(acc, e0, isUser, tblU, tblI, ql);
    }
    acc.x += __shfl_xor(acc.x, 16); acc.x += __shfl_xor(acc.x, 32);
    acc.y += __shfl_xor(acc.y, 16); acc.y += __shfl_xor(acc.y, 32);
    acc.z += __shfl_xor(acc.z, 16); acc.z += __shfl_xor(acc.z, 32);
    acc.w += __shfl_xor(acc.w, 16); acc.w += __shfl_xor(acc.w, 32);
    if (lane < 16) *(float4*)&out[1 + (size_t)n * 256 + (ql << 2)] = acc;
  }
}

// ---------------------------------------------------------------------------
// Transform (round-4 proven design): block = 32 nodes (8/wave), W staged
// per layer in LDS, agg staged from ego slots, coalesced access throughout.
// ---------------------------------------------------------------------------
__global__ __launch_bounds__(256) void transform_kernel(
    const float* __restrict__ user_emb, const float* __restrict__ item_emb,
    const float* __restrict__ W, const float* __restrict__ bvec,
    float* __restrict__ out) {
  __shared__ float Wl[DIM_C * DIM_C];  // 16 KB
  __shared__ float aggS[32][DIM_C];    // 8 KB
  const int tid = threadIdx.x;
  const int wave = tid >> 6;
  const int lane = tid & 63;
  const int n0 = blockIdx.x * 32;

  for (int k = tid; k < 512; k += 256) {
    int row = k >> 4;
    int c4 = k & 15;
    int n = n0 + row;
    float4 a = make_float4(0.f, 0.f, 0.f, 0.f);
    if (n < N_NODES_C) a = *(const float4*)&out[1 + (size_t)n * 256 + c4 * 4];
    *(float4*)&aggS[row][c4 * 4] = a;
  }
  __syncthreads();

  #pragma unroll
  for (int j = 0; j < 8; ++j) {
    int n = n0 + wave * 8 + j;
    if (n < N_NODES_C) {
      float e = (n < N_USERS_C) ? user_emb[(size_t)n * DIM_C + lane]
                                : item_emb[(size_t)(n - N_USERS_C) * DIM_C + lane];
      __builtin_nontemporal_store(e, &out[1 + (size_t)n * 256 + lane]);
    }
  }

  for (int l = 0; l < 3; ++l) {
    __syncthreads();
    {
      const float4* Wg = (const float4*)(W + l * DIM_C * DIM_C);
      float4* Wd = (float4*)Wl;
      #pragma unroll
      for (int i = 0; i < 4; ++i) Wd[tid + i * 256] = Wg[tid + i * 256];
    }
    __syncthreads();

    const float bias = bvec[l * DIM_C + lane];
    float acc[8];
    #pragma unroll
    for (int j = 0; j < 8; ++j) acc[j] = bias;

    #pragma unroll 4
    for (int k4 = 0; k4 < 16; ++k4) {
      const float w0 = Wl[(k4 * 4 + 0) * DIM_C + lane];
      const float w1 = Wl[(k4 * 4 + 1) * DIM_C + lane];
      const float w2 = Wl[(k4 * 4 + 2) * DIM_C + lane];
      const float w3 = Wl[(k4 * 4 + 3) * DIM_C + lane];
      #pragma unroll
      for (int j = 0; j < 8; ++j) {
        const float4 a = *(const float4*)&aggS[wave * 8 + j][k4 * 4];
        acc[j] += a.x * w0 + a.y * w1 + a.z * w2 + a.w * w3;
      }
    }

    #pragma unroll
    for (int j = 0; j < 8; ++j) {
      int n = n0 + wave * 8 + j;
      float s = acc[j];
      s = (s >= 0.f) ? s : 0.2f * s;
      float q = s * s;
      #pragma unroll
      for (int o = 32; o; o >>= 1) q += __shfl_xor(q, o);
      if (n < N_NODES_C) {
        float val = s / fmaxf(sqrtf(q), 1e-12f);
        __builtin_nontemporal_store(
            val, &out[1 + (size_t)n * 256 + (size_t)(l + 1) * 64 + lane]);
      }
    }
  }
}

// ---------------------------------------------------------------------------
// Loss + finalize
// ---------------------------------------------------------------------------
__global__ __launch_bounds__(256) void loss_kernel(
    const float* __restrict__ out, const int* __restrict__ bu,
    const int* __restrict__ bp, const int* __restrict__ bn,
    float* __restrict__ acc) {
  const int wave = threadIdx.x >> 6;
  const int lane = threadIdx.x & 63;
  const int j = blockIdx.x * 4 + wave;
  if (j >= BATCH_C) return;

  const float* urow = out + 1 + (size_t)bu[j] * 256;
  const float* prow = out + 1 + ((size_t)N_USERS_C + bp[j]) * 256;
  const float* nrow = out + 1 + ((size_t)N_USERS_C + bn[j]) * 256;

  float4 u = ((const float4*)urow)[lane];
  float4 pp = ((const float4*)prow)[lane];
  float4 nn = ((const float4*)nrow)[lane];

  float x = u.x * (pp.x - nn.x) + u.y * (pp.y - nn.y) +
            u.z * (pp.z - nn.z) + u.w * (pp.w - nn.w);
  float r = u.x * u.x + u.y * u.y + u.z * u.z + u.w * u.w +
            pp.x * pp.x + pp.y * pp.y + pp.z * pp.z + pp.w * pp.w +
            nn.x * nn.x + nn.y * nn.y + nn.z * nn.z + nn.w * nn.w;

  #pragma unroll
  for (int o = 32; o; o >>= 1) {
    x += __shfl_xor(x, o);
    r += __shfl_xor(r, o);
  }
  if (lane == 0) {
    float ls = fminf(x, 0.f) - log1pf(expf(-fabsf(x)));
    atomicAdd(&acc[0], -ls);
    atomicAdd(&acc[1], 0.5f * r);
  }
}

__global__ void finalize_kernel(const float* __restrict__ acc,
                                float* __restrict__ out) {
  out[0] = acc[0] / (float)BATCH_C + DECAY_C * acc[1] / (float)BATCH_C;
}

// ---------------------------------------------------------------------------
extern "C" void kernel_launch(void* const* d_in, const int* in_sizes, int n_in,
                              void* d_out, int out_size, void* d_ws, size_t ws_size,
                              hipStream_t stream) {
  const float* user_emb = (const float*)d_in[0];
  const float* item_emb = (const float*)d_in[1];
  const float* edge_val = (const float*)d_in[2];
  const float* W        = (const float*)d_in[3];
  const float* bvec     = (const float*)d_in[4];
  const int* edge_row   = (const int*)d_in[5];
  const int* edge_col   = (const int*)d_in[6];
  const int* bu         = (const int*)d_in[7];
  const int* bp         = (const int*)d_in[8];
  const int* bn         = (const int*)d_in[9];

  float* out = (float*)d_out;
  int* ws = (int*)d_ws;
  int* off         = ws + WS_OFF;
  int* bcnt        = ws + WS_BCNT;
  int* bucketStart = ws + WS_BSTART;
  int* cursB1      = ws + WS_CB1;
  float* acc       = (float*)(ws + WS_ACC);
  unsigned* entP   = (unsigned*)(ws + WS_ENT);
  ushort* bf16tab  = (ushort*)(ws + WS_BF16);
  int2* ent1       = (int2*)(out + ENT1_FLOAT_OFF);

  hipMemsetAsync(bcnt, 0, NBUCK * sizeof(int), stream);
  hipMemsetAsync(acc, 0, 2 * sizeof(float), stream);

  cast_kernel<<<(2400000 + 255) / 256, 256, 0, stream>>>(user_emb, item_emb,
                                                         bf16tab);
  bucket_hist_kernel<<<NTILES, 256, 0, stream>>>(edge_row, edge_col, bcnt);
  scan512_kernel<<<1, 512, 0, stream>>>(bcnt, bucketStart, cursB1);
  part1_kernel<<<NTILES, 256, 0, stream>>>(edge_row, edge_col, edge_val,
                                           cursB1, ent1);
  part2_kernel<<<NBUCK, 256, 0, stream>>>(bucketStart, ent1, off, entP);
  gather_kernel<<<2048, 256, 0, stream>>>(bf16tab, off, entP, out);
  transform_kernel<<<(N_NODES_C + 31) / 32, 256, 0, stream>>>(
      user_emb, item_emb, W, bvec, out);
  loss_kernel<<<BATCH_C / 4, 256, 0, stream>>>(out, bu, bp, bn, acc);
  finalize_kernel<<<1, 1, 0, stream>>>(acc, out);
}

// Round 9
// 407.157 us; speedup vs baseline: 1.8180x; 1.1815x over previous
//
#include <hip/hip_runtime.h>
#include <math.h>

#define N_USERS_C 100000
#define N_ITEMS_C 50000
#define N_NODES_C 150000
#define N_EDGES_C 2000000
#define N_ENTRIES_C 4000000
#define DIM_C 64
#define DECAY_C 1e-4f
#define BATCH_C 4096

#define TILE_EDGES 2048
#define NTILES ((N_EDGES_C + TILE_EDGES - 1) / TILE_EDGES)   // 977

// 512 entry-balanced buckets: 256 user buckets x 391 nodes, 256 item x 196.
#define UB_NODES 391
#define IB_NODES 196
#define NBUCK 512
#define B1_DEPTH 14

// ws layout (4-byte units):
//   off[150032] | bcnt[512] | bucketStart[520] | cursB1[512] | acc[24] |
//   wfrag[6144] | entP[4M ints] | bf16 tables (9.6M halfs = 4.8M ints)
#define WS_OFF 0
#define WS_BCNT 150032
#define WS_BSTART 150544
#define WS_CB1 151064
#define WS_ACC 151576
#define WS_WFRAG 151600
#define WS_ENT 157744
#define WS_BF16 4157744
// total 8,957,744 ints = 35.8 MB

// ent1 staging (8B entries, f32 val) in d_out tail, consumed by part2
// before gather/transform overwrite that region (stream-ordered).
#define ENT1_FLOAT_OFF 30400000

typedef __attribute__((ext_vector_type(8))) short short8v;
typedef __attribute__((ext_vector_type(4))) float f32x4;

__device__ __forceinline__ unsigned bf16_bits(float v) {
  unsigned u = __float_as_uint(v);
  return (u + 0x8000u) >> 16;
}

__device__ __forceinline__ short8v as_short8(uint4 u) {
  union { uint4 u4; short8v s8; } x;
  x.u4 = u;
  return x.s8;
}

// ---------------------------------------------------------------------------
// Kernel 0: cast both tables to bf16 (user table then item table, contiguous)
// ---------------------------------------------------------------------------
__global__ __launch_bounds__(256) void cast_kernel(
    const float* __restrict__ user_emb, const float* __restrict__ item_emb,
    ushort* __restrict__ h) {
  const int t = blockIdx.x * 256 + threadIdx.x;  // one float4 per thread
  const int nUser4 = N_USERS_C * DIM_C / 4;
  const int nTot4 = (N_USERS_C + N_ITEMS_C) * DIM_C / 4;
  if (t >= nTot4) return;
  float4 v = (t < nUser4) ? ((const float4*)user_emb)[t]
                          : ((const float4*)item_emb)[t - nUser4];
  ushort4 o;
  o.x = (ushort)bf16_bits(v.x);
  o.y = (ushort)bf16_bits(v.y);
  o.z = (ushort)bf16_bits(v.z);
  o.w = (ushort)bf16_bits(v.w);
  *(ushort4*)&h[(size_t)t * 4] = o;
}

// ---------------------------------------------------------------------------
// Kernel 0b: pack W into 24 MFMA B-fragments (bf16).
// frag f = layer*8 + t*2 + s  (t = N-tile 0..3, s = K-step 0..1)
// lane l holds k = s*32 + (l>>4)*8 + e, n = t*16 + (l&15), e = 0..7
// ---------------------------------------------------------------------------
__global__ __launch_bounds__(256) void wprep_kernel(
    const float* __restrict__ W, uint4* __restrict__ wfrag) {
  const int g = blockIdx.x * 256 + threadIdx.x;
  if (g >= 24 * 64) return;
  const int f = g >> 6, l = g & 63;
  const int layer = f >> 3, rem = f & 7, t = rem >> 1, s = rem & 1;
  const int n = t * 16 + (l & 15);
  const int k0 = s * 32 + (l >> 4) * 8;
  const float* base = W + layer * DIM_C * DIM_C + n;  // stride 64 per k
  unsigned r[4];
  #pragma unroll
  for (int j = 0; j < 4; ++j) {
    unsigned lo = bf16_bits(base[(size_t)(k0 + 2 * j) * DIM_C]);
    unsigned hi = bf16_bits(base[(size_t)(k0 + 2 * j + 1) * DIM_C]);
    r[j] = lo | (hi << 16);
  }
  wfrag[g] = make_uint4(r[0], r[1], r[2], r[3]);
}

// ---------------------------------------------------------------------------
// Kernel 1: bucket-level histogram (512 bins, LDS-aggregated)
// ---------------------------------------------------------------------------
__global__ __launch_bounds__(256) void bucket_hist_kernel(
    const int* __restrict__ edge_row, const int* __restrict__ edge_col,
    int* __restrict__ bcnt) {
  __shared__ int h[NBUCK];
  const int tid = threadIdx.x;
  for (int i = tid; i < NBUCK; i += 256) h[i] = 0;
  __syncthreads();
  const int base = blockIdx.x * TILE_EDGES;
  #pragma unroll
  for (int k = 0; k < 8; ++k) {
    int e = base + k * 256 + tid;
    if (e < N_EDGES_C) {
      atomicAdd(&h[(int)((unsigned)edge_row[e] / UB_NODES)], 1);
      atomicAdd(&h[256 + (int)((unsigned)edge_col[e] / IB_NODES)], 1);
    }
  }
  __syncthreads();
  for (int i = tid; i < NBUCK; i += 256) {
    int v = h[i];
    if (v) atomicAdd(&bcnt[i], v);
  }
}

// ---------------------------------------------------------------------------
// Kernel 2: exclusive scan of 512 bucket counts (single block)
// ---------------------------------------------------------------------------
__global__ __launch_bounds__(512) void scan512_kernel(
    const int* __restrict__ bcnt, int* __restrict__ bucketStart,
    int* __restrict__ cursB1) {
  __shared__ int ts[512];
  const int t = threadIdx.x;
  int c = bcnt[t];
  ts[t] = c;
  __syncthreads();
  #pragma unroll
  for (int o = 1; o < 512; o <<= 1) {
    int y = (t >= o) ? ts[t - o] : 0;
    __syncthreads();
    ts[t] += y;
    __syncthreads();
  }
  int excl = ts[t] - c;
  bucketStart[t] = excl;
  cursB1[t] = excl;
  if (t == 511) bucketStart[512] = ts[511];
}

// ---------------------------------------------------------------------------
// Phase B1: bin entries into 512 buckets (LDS staging + chunked flush).
// ent1 packing: x = src | (local_node << 17), y = f32 val bits.
// ---------------------------------------------------------------------------
__global__ __launch_bounds__(256) void part1_kernel(
    const int* __restrict__ edge_row, const int* __restrict__ edge_col,
    const float* __restrict__ edge_val, int* __restrict__ cursB1,
    int2* __restrict__ ent1) {
  __shared__ int2 stg[NBUCK][B1_DEPTH];  // 56 KB
  __shared__ int scnt[NBUCK];
  const int tid = threadIdx.x;
  for (int i = tid; i < NBUCK; i += 256) scnt[i] = 0;
  __syncthreads();

  const int base = blockIdx.x * TILE_EDGES;
  #pragma unroll
  for (int k = 0; k < 8; ++k) {
    int e = base + k * 256 + tid;
    if (e < N_EDGES_C) {
      int r = edge_row[e];
      int c = edge_col[e];
      int vb = __float_as_int(edge_val[e]);
      int ub = (int)((unsigned)r / UB_NODES);
      int2 E1 = make_int2(c | ((r - ub * UB_NODES) << 17), vb);
      int s1 = atomicAdd(&scnt[ub], 1);
      if (s1 < B1_DEPTH) stg[ub][s1] = E1;
      else ent1[atomicAdd(&cursB1[ub], 1)] = E1;
      int ib = (int)((unsigned)c / IB_NODES);
      int2 E2 = make_int2(r | ((c - ib * IB_NODES) << 17), vb);
      ib += 256;
      int s2 = atomicAdd(&scnt[ib], 1);
      if (s2 < B1_DEPTH) stg[ib][s2] = E2;
      else ent1[atomicAdd(&cursB1[ib], 1)] = E2;
    }
  }
  __syncthreads();
  for (int i = tid; i < NBUCK; i += 256) {
    int cn = scnt[i];
    if (cn > B1_DEPTH) cn = B1_DEPTH;
    if (cn) {
      int p = atomicAdd(&cursB1[i], cn);
      for (int j = 0; j < cn; ++j) ent1[p + j] = stg[i][j];
    }
  }
}

// ---------------------------------------------------------------------------
// Phase B2: per-bucket local node histogram + LDS scan -> writes off[]
// coalesced, then scatters packed 4B entries via LDS cursor atomics.
// ---------------------------------------------------------------------------
__global__ __launch_bounds__(256) void part2_kernel(
    const int* __restrict__ bucketStart, const int2* __restrict__ ent1,
    int* __restrict__ off, unsigned* __restrict__ entP) {
  __shared__ int lhist[512];
  __shared__ int lexcl[512];
  __shared__ int ps[256];
  const int b = blockIdx.x;
  const int tid = threadIdx.x;
  int nb, nodes;
  if (b < 256) {
    nb = b * UB_NODES;
    int e = (b + 1) * UB_NODES;
    if (e > N_USERS_C) e = N_USERS_C;
    nodes = e - nb;
  } else {
    nb = N_USERS_C + (b - 256) * IB_NODES;
    int e = N_USERS_C + (b - 255) * IB_NODES;
    if (e > N_NODES_C) e = N_NODES_C;
    nodes = e - nb;
  }
  const int start = bucketStart[b];
  const int end = bucketStart[b + 1];

  for (int i = tid; i < 512; i += 256) lhist[i] = 0;
  __syncthreads();

  for (int i = start + tid; i < end; i += 256)
    atomicAdd(&lhist[(unsigned)ent1[i].x >> 17], 1);
  __syncthreads();

  int a0 = lhist[2 * tid];
  int a1 = lhist[2 * tid + 1];
  ps[tid] = a0 + a1;
  __syncthreads();
  #pragma unroll
  for (int o = 1; o < 256; o <<= 1) {
    int y = (tid >= o) ? ps[tid - o] : 0;
    __syncthreads();
    ps[tid] += y;
    __syncthreads();
  }
  int e0 = ps[tid] - a0 - a1;
  lexcl[2 * tid] = e0;
  lexcl[2 * tid + 1] = e0 + a0;
  __syncthreads();

  for (int t = tid; t < nodes; t += 256) off[nb + t] = start + lexcl[t];
  if (b == NBUCK - 1 && tid == 0) off[N_NODES_C] = N_ENTRIES_C;

  for (int i = tid; i < 512; i += 256) lhist[i] = lexcl[i];
  __syncthreads();

  const bool isUser = (b < 256);
  for (int i = start + tid; i < end; i += 256) {
    int2 E = ent1[i];
    int local = (int)((unsigned)E.x >> 17);
    int src = E.x & 0x1FFFF;
    unsigned hb = bf16_bits(__int_as_float(E.y));
    unsigned P;
    if (isUser) {
      P = (hb << 16) | (unsigned)src;
    } else {
      P = (((hb & 0xFFFEu) | ((unsigned)src & 1u)) << 16) |
          ((unsigned)src >> 1);
    }
    int p = start + atomicAdd(&lhist[local], 1);
    entP[p] = P;
  }
}

// ---------------------------------------------------------------------------
// Gather: streaming, quarter-wave (16 lanes x 8B bf16x4) per entry,
// 4 entries in flight per quarter -> 16 rows in flight per wave.
// Writes agg row as 64 bf16 (128B) at float offset +4 within the node's
// out row (16B aligned); transform consumes it before overwriting ego.
// ---------------------------------------------------------------------------
__device__ __forceinline__ void acc_row(float4& acc, unsigned E, bool isUser,
                                        const ushort* __restrict__ tblU,
                                        const ushort* __restrict__ tblI,
                                        int ql) {
  unsigned src;
  float v;
  const ushort* t;
  if (isUser) {
    src = E & 0xFFFFu;
    v = __uint_as_float(E & 0xFFFF0000u);
    t = tblI;
  } else {
    src = ((E & 0xFFFFu) << 1) | ((E >> 16) & 1u);
    v = __uint_as_float(E & 0xFFFE0000u);
    t = tblU;
  }
  uint2 q = *(const uint2*)(t + ((size_t)src << 6) + (ql << 2));
  acc.x += v * __uint_as_float(q.x << 16);
  acc.y += v * __uint_as_float(q.x & 0xFFFF0000u);
  acc.z += v * __uint_as_float(q.y << 16);
  acc.w += v * __uint_as_float(q.y & 0xFFFF0000u);
}

__global__ __launch_bounds__(256) void gather_kernel(
    const ushort* __restrict__ bf16tab, const int* __restrict__ off,
    const unsigned* __restrict__ entP, float* __restrict__ out) {
  const int lane = threadIdx.x & 63;
  const int quarter = lane >> 4;
  const int ql = lane & 15;
  const int wave0 = (blockIdx.x * 256 + threadIdx.x) >> 6;
  const int nWaves = gridDim.x * 4;
  const ushort* tblU = bf16tab;
  const ushort* tblI = bf16tab + (size_t)N_USERS_C * DIM_C;

  for (int n = wave0; n < N_NODES_C; n += nWaves) {
    const bool isUser = (n < N_USERS_C);
    int i = off[n] + quarter;
    const int end = off[n + 1];
    float4 acc = make_float4(0.f, 0.f, 0.f, 0.f);
    for (; i + 12 < end; i += 16) {
      unsigned e0 = entP[i];
      unsigned e1 = entP[i + 4];
      unsigned e2 = entP[i + 8];
      unsigned e3 = entP[i + 12];
      acc_row(acc, e0, isUser, tblU, tblI, ql);
      acc_row(acc, e1, isUser, tblU, tblI, ql);
      acc_row(acc, e2, isUser, tblU, tblI, ql);
      acc_row(acc, e3, isUser, tblU, tblI, ql);
    }
    for (; i < end; i += 4) {
      unsigned e0 = entP[i];
      acc_row(acc, e0, isUser, tblU, tblI, ql);
    }
    acc.x += __shfl_xor(acc.x, 16); acc.x += __shfl_xor(acc.x, 32);
    acc.y += __shfl_xor(acc.y, 16); acc.y += __shfl_xor(acc.y, 32);
    acc.z += __shfl_xor(acc.z, 16); acc.z += __shfl_xor(acc.z, 32);
    acc.w += __shfl_xor(acc.w, 16); acc.w += __shfl_xor(acc.w, 32);
    if (lane < 16) {
      uint2 o;
      o.x = bf16_bits(acc.x) | (bf16_bits(acc.y) << 16);
      o.y = bf16_bits(acc.z) | (bf16_bits(acc.w) << 16);
      ((uint2*)(out + 4 + (size_t)n * 256))[ql] = o;
    }
  }
}

// ---------------------------------------------------------------------------
// Transform v3 (MFMA): wave = 16 nodes. A = agg rows (bf16, from ego-slot
// prefix), B = W fragments (LDS, staged from wfragG). 24 MFMA + in-register
// epilogue (bias, leaky, 16-lane shfl row-norm). Ego copied last.
// ---------------------------------------------------------------------------
__global__ __launch_bounds__(256) void transform_kernel(
    const float* __restrict__ user_emb, const float* __restrict__ item_emb,
    const uint4* __restrict__ wfragG, const float* __restrict__ bvec,
    float* __restrict__ out) {
  __shared__ uint4 Wf[24 * 64];  // 24 KB
  const int tid = threadIdx.x;
  for (int i = tid; i < 24 * 64; i += 256) Wf[i] = wfragG[i];
  __syncthreads();

  const int wave = tid >> 6;
  const int lane = tid & 63;
  const int nb = blockIdx.x * 64 + wave * 16;
  if (nb >= N_NODES_C) return;  // whole-wave guard (150000 % 16 == 0)
  const int q = lane >> 4;
  const int col = lane & 15;

  // A fragments: lane reads row (nb+col), k = q*8..q*8+7 (s=0) and +32 (s=1)
  const uint4* aggp = (const uint4*)(out + 4 + (size_t)(nb + col) * 256);
  short8v A0 = as_short8(aggp[q]);
  short8v A1 = as_short8(aggp[q + 4]);

  for (int l = 0; l < 3; ++l) {
    f32x4 c[4];
    #pragma unroll
    for (int t = 0; t < 4; ++t) c[t] = (f32x4){0.f, 0.f, 0.f, 0.f};
    const uint4* wl = &Wf[l * 8 * 64];
    #pragma unroll
    for (int t = 0; t < 4; ++t) {
      c[t] = __builtin_amdgcn_mfma_f32_16x16x32_bf16(
          A0, as_short8(wl[(t * 2 + 0) * 64 + lane]), c[t], 0, 0, 0);
      c[t] = __builtin_amdgcn_mfma_f32_16x16x32_bf16(
          A1, as_short8(wl[(t * 2 + 1) * 64 + lane]), c[t], 0, 0, 0);
    }

    float sq[4] = {0.f, 0.f, 0.f, 0.f};
    #pragma unroll
    for (int t = 0; t < 4; ++t) {
      const float bt = bvec[l * DIM_C + t * 16 + col];
      #pragma unroll
      for (int r = 0; r < 4; ++r) {
        float v = c[t][r] + bt;
        v = (v >= 0.f) ? v : 0.2f * v;
        c[t][r] = v;
        sq[r] += v * v;
      }
    }
    #pragma unroll
    for (int r = 0; r < 4; ++r) {
      #pragma unroll
      for (int m = 1; m < 16; m <<= 1) sq[r] += __shfl_xor(sq[r], m);
      sq[r] = 1.0f / fmaxf(sqrtf(sq[r]), 1e-12f);
    }
    #pragma unroll
    for (int t = 0; t < 4; ++t) {
      #pragma unroll
      for (int r = 0; r < 4; ++r) {
        const int node = nb + q * 4 + r;
        out[1 + (size_t)node * 256 + (size_t)(l + 1) * 64 + t * 16 + col] =
            c[t][r] * sq[r];
      }
    }
  }

  // ego copy (overwrites the agg prefix; same-wave alias order is safe)
  for (int idx = lane; idx < 16 * DIM_C; idx += 64) {
    const int node = nb + (idx >> 6);
    const int cc = idx & 63;
    float e = (node < N_USERS_C)
                  ? user_emb[(size_t)node * DIM_C + cc]
                  : item_emb[(size_t)(node - N_USERS_C) * DIM_C + cc];
    out[1 + (size_t)node * 256 + cc] = e;
  }
}

// ---------------------------------------------------------------------------
// Loss + finalize
// ---------------------------------------------------------------------------
__global__ __launch_bounds__(256) void loss_kernel(
    const float* __restrict__ out, const int* __restrict__ bu,
    const int* __restrict__ bp, const int* __restrict__ bn,
    float* __restrict__ acc) {
  const int wave = threadIdx.x >> 6;
  const int lane = threadIdx.x & 63;
  const int j = blockIdx.x * 4 + wave;
  if (j >= BATCH_C) return;

  const float* urow = out + 1 + (size_t)bu[j] * 256;
  const float* prow = out + 1 + ((size_t)N_USERS_C + bp[j]) * 256;
  const float* nrow = out + 1 + ((size_t)N_USERS_C + bn[j]) * 256;

  float4 u = ((const float4*)urow)[lane];
  float4 pp = ((const float4*)prow)[lane];
  float4 nn = ((const float4*)nrow)[lane];

  float x = u.x * (pp.x - nn.x) + u.y * (pp.y - nn.y) +
            u.z * (pp.z - nn.z) + u.w * (pp.w - nn.w);
  float r = u.x * u.x + u.y * u.y + u.z * u.z + u.w * u.w +
            pp.x * pp.x + pp.y * pp.y + pp.z * pp.z + pp.w * pp.w +
            nn.x * nn.x + nn.y * nn.y + nn.z * nn.z + nn.w * nn.w;

  #pragma unroll
  for (int o = 32; o; o >>= 1) {
    x += __shfl_xor(x, o);
    r += __shfl_xor(r, o);
  }
  if (lane == 0) {
    float ls = fminf(x, 0.f) - log1pf(expf(-fabsf(x)));
    atomicAdd(&acc[0], -ls);
    atomicAdd(&acc[1], 0.5f * r);
  }
}

__global__ void finalize_kernel(const float* __restrict__ acc,
                                float* __restrict__ out) {
  out[0] = acc[0] / (float)BATCH_C + DECAY_C * acc[1] / (float)BATCH_C;
}

// ---------------------------------------------------------------------------
extern "C" void kernel_launch(void* const* d_in, const int* in_sizes, int n_in,
                              void* d_out, int out_size, void* d_ws, size_t ws_size,
                              hipStream_t stream) {
  const float* user_emb = (const float*)d_in[0];
  const float* item_emb = (const float*)d_in[1];
  const float* edge_val = (const float*)d_in[2];
  const float* W        = (const float*)d_in[3];
  const float* bvec     = (const float*)d_in[4];
  const int* edge_row   = (const int*)d_in[5];
  const int* edge_col   = (const int*)d_in[6];
  const int* bu         = (const int*)d_in[7];
  const int* bp         = (const int*)d_in[8];
  const int* bn         = (const int*)d_in[9];

  float* out = (float*)d_out;
  int* ws = (int*)d_ws;
  int* off         = ws + WS_OFF;
  int* bcnt        = ws + WS_BCNT;
  int* bucketStart = ws + WS_BSTART;
  int* cursB1      = ws + WS_CB1;
  float* acc       = (float*)(ws + WS_ACC);
  uint4* wfrag     = (uint4*)(ws + WS_WFRAG);
  unsigned* entP   = (unsigned*)(ws + WS_ENT);
  ushort* bf16tab  = (ushort*)(ws + WS_BF16);
  int2* ent1       = (int2*)(out + ENT1_FLOAT_OFF);

  hipMemsetAsync(bcnt, 0, NBUCK * sizeof(int), stream);
  hipMemsetAsync(acc, 0, 2 * sizeof(float), stream);

  cast_kernel<<<(2400000 + 255) / 256, 256, 0, stream>>>(user_emb, item_emb,
                                                         bf16tab);
  wprep_kernel<<<6, 256, 0, stream>>>(W, wfrag);
  bucket_hist_kernel<<<NTILES, 256, 0, stream>>>(edge_row, edge_col, bcnt);
  scan512_kernel<<<1, 512, 0, stream>>>(bcnt, bucketStart, cursB1);
  part1_kernel<<<NTILES, 256, 0, stream>>>(edge_row, edge_col, edge_val,
                                           cursB1, ent1);
  part2_kernel<<<NBUCK, 256, 0, stream>>>(bucketStart, ent1, off, entP);
  gather_kernel<<<2048, 256, 0, stream>>>(bf16tab, off, entP, out);
  transform_kernel<<<(N_NODES_C + 63) / 64, 256, 0, stream>>>(
      user_emb, item_emb, wfrag, bvec, out);
  loss_kernel<<<BATCH_C / 4, 256, 0, stream>>>(out, bu, bp, bn, acc);
  finalize_kernel<<<1, 1, 0, stream>>>(acc, out);
}

// Round 10
// 286.399 us; speedup vs baseline: 2.5846x; 1.4216x over previous
//
#include <hip/hip_runtime.h>
#include <math.h>

#define N_USERS_C 100000
#define N_ITEMS_C 50000
#define N_NODES_C 150000
#define N_EDGES_C 2000000
#define N_ENTRIES_C 4000000
#define DIM_C 64
#define DECAY_C 1e-4f
#define BATCH_C 4096

#define TILE_EDGES 2048
#define NTILES ((N_EDGES_C + TILE_EDGES - 1) / TILE_EDGES)   // 977

// 512 entry-balanced buckets: 256 user buckets x 391 nodes, 256 item x 196.
#define UB_NODES 391
#define IB_NODES 196
#define NBUCK 512
#define B1_DEPTH 14

#define LOSS_NB (BATCH_C / 4)  // 1024 blocks, 4 batch elems (waves) each

// ws layout (4-byte units):
//   off[150032] | bcnt[512] | bucketStart[520] | cursB1[512] | acc[24] |
//   wfrag[6144] | part[2048] | entP[4M ints] | bf16 tables (4.8M ints)
#define WS_OFF 0
#define WS_BCNT 150032
#define WS_BSTART 150544
#define WS_CB1 151064
#define WS_ACC 151576
#define WS_WFRAG 151600
#define WS_PART 157744
#define WS_ENT 159792
#define WS_BF16 4159792
// total 8,959,792 ints = 35.84 MB

// ent1 staging (8B entries, f32 val) in d_out tail, consumed by part2
// before gather/transform overwrite that region (stream-ordered).
#define ENT1_FLOAT_OFF 30400000

typedef __attribute__((ext_vector_type(8))) short short8v;
typedef __attribute__((ext_vector_type(4))) float f32x4;

__device__ __forceinline__ unsigned bf16_bits(float v) {
  unsigned u = __float_as_uint(v);
  return (u + 0x8000u) >> 16;
}

__device__ __forceinline__ short8v as_short8(uint4 u) {
  union { uint4 u4; short8v s8; } x;
  x.u4 = u;
  return x.s8;
}

// ---------------------------------------------------------------------------
// Kernel 0: cast both tables to bf16 (user table then item table, contiguous)
// ---------------------------------------------------------------------------
__global__ __launch_bounds__(256) void cast_kernel(
    const float* __restrict__ user_emb, const float* __restrict__ item_emb,
    ushort* __restrict__ h) {
  const int t = blockIdx.x * 256 + threadIdx.x;  // one float4 per thread
  const int nUser4 = N_USERS_C * DIM_C / 4;
  const int nTot4 = (N_USERS_C + N_ITEMS_C) * DIM_C / 4;
  if (t >= nTot4) return;
  float4 v = (t < nUser4) ? ((const float4*)user_emb)[t]
                          : ((const float4*)item_emb)[t - nUser4];
  ushort4 o;
  o.x = (ushort)bf16_bits(v.x);
  o.y = (ushort)bf16_bits(v.y);
  o.z = (ushort)bf16_bits(v.z);
  o.w = (ushort)bf16_bits(v.w);
  *(ushort4*)&h[(size_t)t * 4] = o;
}

// ---------------------------------------------------------------------------
// Kernel 0b: pack W into 24 MFMA B-fragments (bf16).
// ---------------------------------------------------------------------------
__global__ __launch_bounds__(256) void wprep_kernel(
    const float* __restrict__ W, uint4* __restrict__ wfrag) {
  const int g = blockIdx.x * 256 + threadIdx.x;
  if (g >= 24 * 64) return;
  const int f = g >> 6, l = g & 63;
  const int layer = f >> 3, rem = f & 7, t = rem >> 1, s = rem & 1;
  const int n = t * 16 + (l & 15);
  const int k0 = s * 32 + (l >> 4) * 8;
  const float* base = W + layer * DIM_C * DIM_C + n;  // stride 64 per k
  unsigned r[4];
  #pragma unroll
  for (int j = 0; j < 4; ++j) {
    unsigned lo = bf16_bits(base[(size_t)(k0 + 2 * j) * DIM_C]);
    unsigned hi = bf16_bits(base[(size_t)(k0 + 2 * j + 1) * DIM_C]);
    r[j] = lo | (hi << 16);
  }
  wfrag[g] = make_uint4(r[0], r[1], r[2], r[3]);
}

// ---------------------------------------------------------------------------
// Kernel 1: bucket-level histogram (512 bins, LDS-aggregated)
// ---------------------------------------------------------------------------
__global__ __launch_bounds__(256) void bucket_hist_kernel(
    const int* __restrict__ edge_row, const int* __restrict__ edge_col,
    int* __restrict__ bcnt) {
  __shared__ int h[NBUCK];
  const int tid = threadIdx.x;
  for (int i = tid; i < NBUCK; i += 256) h[i] = 0;
  __syncthreads();
  const int base = blockIdx.x * TILE_EDGES;
  #pragma unroll
  for (int k = 0; k < 8; ++k) {
    int e = base + k * 256 + tid;
    if (e < N_EDGES_C) {
      atomicAdd(&h[(int)((unsigned)edge_row[e] / UB_NODES)], 1);
      atomicAdd(&h[256 + (int)((unsigned)edge_col[e] / IB_NODES)], 1);
    }
  }
  __syncthreads();
  for (int i = tid; i < NBUCK; i += 256) {
    int v = h[i];
    if (v) atomicAdd(&bcnt[i], v);
  }
}

// ---------------------------------------------------------------------------
// Kernel 2: exclusive scan of 512 bucket counts (single block)
// ---------------------------------------------------------------------------
__global__ __launch_bounds__(512) void scan512_kernel(
    const int* __restrict__ bcnt, int* __restrict__ bucketStart,
    int* __restrict__ cursB1) {
  __shared__ int ts[512];
  const int t = threadIdx.x;
  int c = bcnt[t];
  ts[t] = c;
  __syncthreads();
  #pragma unroll
  for (int o = 1; o < 512; o <<= 1) {
    int y = (t >= o) ? ts[t - o] : 0;
    __syncthreads();
    ts[t] += y;
    __syncthreads();
  }
  int excl = ts[t] - c;
  bucketStart[t] = excl;
  cursB1[t] = excl;
  if (t == 511) bucketStart[512] = ts[511];
}

// ---------------------------------------------------------------------------
// Phase B1: bin entries into 512 buckets (LDS staging + chunked flush).
// ---------------------------------------------------------------------------
__global__ __launch_bounds__(256) void part1_kernel(
    const int* __restrict__ edge_row, const int* __restrict__ edge_col,
    const float* __restrict__ edge_val, int* __restrict__ cursB1,
    int2* __restrict__ ent1) {
  __shared__ int2 stg[NBUCK][B1_DEPTH];  // 56 KB
  __shared__ int scnt[NBUCK];
  const int tid = threadIdx.x;
  for (int i = tid; i < NBUCK; i += 256) scnt[i] = 0;
  __syncthreads();

  const int base = blockIdx.x * TILE_EDGES;
  #pragma unroll
  for (int k = 0; k < 8; ++k) {
    int e = base + k * 256 + tid;
    if (e < N_EDGES_C) {
      int r = edge_row[e];
      int c = edge_col[e];
      int vb = __float_as_int(edge_val[e]);
      int ub = (int)((unsigned)r / UB_NODES);
      int2 E1 = make_int2(c | ((r - ub * UB_NODES) << 17), vb);
      int s1 = atomicAdd(&scnt[ub], 1);
      if (s1 < B1_DEPTH) stg[ub][s1] = E1;
      else ent1[atomicAdd(&cursB1[ub], 1)] = E1;
      int ib = (int)((unsigned)c / IB_NODES);
      int2 E2 = make_int2(r | ((c - ib * IB_NODES) << 17), vb);
      ib += 256;
      int s2 = atomicAdd(&scnt[ib], 1);
      if (s2 < B1_DEPTH) stg[ib][s2] = E2;
      else ent1[atomicAdd(&cursB1[ib], 1)] = E2;
    }
  }
  __syncthreads();
  for (int i = tid; i < NBUCK; i += 256) {
    int cn = scnt[i];
    if (cn > B1_DEPTH) cn = B1_DEPTH;
    if (cn) {
      int p = atomicAdd(&cursB1[i], cn);
      for (int j = 0; j < cn; ++j) ent1[p + j] = stg[i][j];
    }
  }
}

// ---------------------------------------------------------------------------
// Phase B2: per-bucket local node histogram + LDS scan -> writes off[]
// coalesced, then scatters packed 4B entries via LDS cursor atomics.
// ---------------------------------------------------------------------------
__global__ __launch_bounds__(256) void part2_kernel(
    const int* __restrict__ bucketStart, const int2* __restrict__ ent1,
    int* __restrict__ off, unsigned* __restrict__ entP) {
  __shared__ int lhist[512];
  __shared__ int lexcl[512];
  __shared__ int ps[256];
  const int b = blockIdx.x;
  const int tid = threadIdx.x;
  int nb, nodes;
  if (b < 256) {
    nb = b * UB_NODES;
    int e = (b + 1) * UB_NODES;
    if (e > N_USERS_C) e = N_USERS_C;
    nodes = e - nb;
  } else {
    nb = N_USERS_C + (b - 256) * IB_NODES;
    int e = N_USERS_C + (b - 255) * IB_NODES;
    if (e > N_NODES_C) e = N_NODES_C;
    nodes = e - nb;
  }
  const int start = bucketStart[b];
  const int end = bucketStart[b + 1];

  for (int i = tid; i < 512; i += 256) lhist[i] = 0;
  __syncthreads();

  for (int i = start + tid; i < end; i += 256)
    atomicAdd(&lhist[(unsigned)ent1[i].x >> 17], 1);
  __syncthreads();

  int a0 = lhist[2 * tid];
  int a1 = lhist[2 * tid + 1];
  ps[tid] = a0 + a1;
  __syncthreads();
  #pragma unroll
  for (int o = 1; o < 256; o <<= 1) {
    int y = (tid >= o) ? ps[tid - o] : 0;
    __syncthreads();
    ps[tid] += y;
    __syncthreads();
  }
  int e0 = ps[tid] - a0 - a1;
  lexcl[2 * tid] = e0;
  lexcl[2 * tid + 1] = e0 + a0;
  __syncthreads();

  for (int t = tid; t < nodes; t += 256) off[nb + t] = start + lexcl[t];
  if (b == NBUCK - 1 && tid == 0) off[N_NODES_C] = N_ENTRIES_C;

  for (int i = tid; i < 512; i += 256) lhist[i] = lexcl[i];
  __syncthreads();

  const bool isUser = (b < 256);
  for (int i = start + tid; i < end; i += 256) {
    int2 E = ent1[i];
    int local = (int)((unsigned)E.x >> 17);
    int src = E.x & 0x1FFFF;
    unsigned hb = bf16_bits(__int_as_float(E.y));
    unsigned P;
    if (isUser) {
      P = (hb << 16) | (unsigned)src;
    } else {
      P = (((hb & 0xFFFEu) | ((unsigned)src & 1u)) << 16) |
          ((unsigned)src >> 1);
    }
    int p = start + atomicAdd(&lhist[local], 1);
    entP[p] = P;
  }
}

// ---------------------------------------------------------------------------
// Gather: streaming, quarter-wave (16 lanes x 8B bf16x4) per entry,
// 4 entries in flight per quarter -> 16 rows in flight per wave.
// Writes agg row as 64 bf16 (128B) at float offset +4 within the node's
// out row; transform consumes it before overwriting ego.
// ---------------------------------------------------------------------------
__device__ __forceinline__ void acc_row(float4& acc, unsigned E, bool isUser,
                                        const ushort* __restrict__ tblU,
                                        const ushort* __restrict__ tblI,
                                        int ql) {
  unsigned src;
  float v;
  const ushort* t;
  if (isUser) {
    src = E & 0xFFFFu;
    v = __uint_as_float(E & 0xFFFF0000u);
    t = tblI;
  } else {
    src = ((E & 0xFFFFu) << 1) | ((E >> 16) & 1u);
    v = __uint_as_float(E & 0xFFFE0000u);
    t = tblU;
  }
  uint2 q = *(const uint2*)(t + ((size_t)src << 6) + (ql << 2));
  acc.x += v * __uint_as_float(q.x << 16);
  acc.y += v * __uint_as_float(q.x & 0xFFFF0000u);
  acc.z += v * __uint_as_float(q.y << 16);
  acc.w += v * __uint_as_float(q.y & 0xFFFF0000u);
}

__global__ __launch_bounds__(256) void gather_kernel(
    const ushort* __restrict__ bf16tab, const int* __restrict__ off,
    const unsigned* __restrict__ entP, float* __restrict__ out) {
  const int lane = threadIdx.x & 63;
  const int quarter = lane >> 4;
  const int ql = lane & 15;
  const int wave0 = (blockIdx.x * 256 + threadIdx.x) >> 6;
  const int nWaves = gridDim.x * 4;
  const ushort* tblU = bf16tab;
  const ushort* tblI = bf16tab + (size_t)N_USERS_C * DIM_C;

  for (int n = wave0; n < N_NODES_C; n += nWaves) {
    const bool isUser = (n < N_USERS_C);
    int i = off[n] + quarter;
    const int end = off[n + 1];
    float4 acc = make_float4(0.f, 0.f, 0.f, 0.f);
    for (; i + 12 < end; i += 16) {
      unsigned e0 = entP[i];
      unsigned e1 = entP[i + 4];
      unsigned e2 = entP[i + 8];
      unsigned e3 = entP[i + 12];
      acc_row(acc, e0, isUser, tblU, tblI, ql);
      acc_row(acc, e1, isUser, tblU, tblI, ql);
      acc_row(acc, e2, isUser, tblU, tblI, ql);
      acc_row(acc, e3, isUser, tblU, tblI, ql);
    }
    for (; i < end; i += 4) {
      unsigned e0 = entP[i];
      acc_row(acc, e0, isUser, tblU, tblI, ql);
    }
    acc.x += __shfl_xor(acc.x, 16); acc.x += __shfl_xor(acc.x, 32);
    acc.y += __shfl_xor(acc.y, 16); acc.y += __shfl_xor(acc.y, 32);
    acc.z += __shfl_xor(acc.z, 16); acc.z += __shfl_xor(acc.z, 32);
    acc.w += __shfl_xor(acc.w, 16); acc.w += __shfl_xor(acc.w, 32);
    if (lane < 16) {
      uint2 o;
      o.x = bf16_bits(acc.x) | (bf16_bits(acc.y) << 16);
      o.y = bf16_bits(acc.z) | (bf16_bits(acc.w) << 16);
      ((uint2*)(out + 4 + (size_t)n * 256))[ql] = o;
    }
  }
}

// ---------------------------------------------------------------------------
// Transform v3 (MFMA): wave = 16 nodes. 24 MFMA + in-register epilogue.
// ---------------------------------------------------------------------------
__global__ __launch_bounds__(256) void transform_kernel(
    const float* __restrict__ user_emb, const float* __restrict__ item_emb,
    const uint4* __restrict__ wfragG, const float* __restrict__ bvec,
    float* __restrict__ out) {
  __shared__ uint4 Wf[24 * 64];  // 24 KB
  const int tid = threadIdx.x;
  for (int i = tid; i < 24 * 64; i += 256) Wf[i] = wfragG[i];
  __syncthreads();

  const int wave = tid >> 6;
  const int lane = tid & 63;
  const int nb = blockIdx.x * 64 + wave * 16;
  if (nb >= N_NODES_C) return;  // whole-wave guard (150000 % 16 == 0)
  const int q = lane >> 4;
  const int col = lane & 15;

  const uint4* aggp = (const uint4*)(out + 4 + (size_t)(nb + col) * 256);
  short8v A0 = as_short8(aggp[q]);
  short8v A1 = as_short8(aggp[q + 4]);

  for (int l = 0; l < 3; ++l) {
    f32x4 c[4];
    #pragma unroll
    for (int t = 0; t < 4; ++t) c[t] = (f32x4){0.f, 0.f, 0.f, 0.f};
    const uint4* wl = &Wf[l * 8 * 64];
    #pragma unroll
    for (int t = 0; t < 4; ++t) {
      c[t] = __builtin_amdgcn_mfma_f32_16x16x32_bf16(
          A0, as_short8(wl[(t * 2 + 0) * 64 + lane]), c[t], 0, 0, 0);
      c[t] = __builtin_amdgcn_mfma_f32_16x16x32_bf16(
          A1, as_short8(wl[(t * 2 + 1) * 64 + lane]), c[t], 0, 0, 0);
    }

    float sq[4] = {0.f, 0.f, 0.f, 0.f};
    #pragma unroll
    for (int t = 0; t < 4; ++t) {
      const float bt = bvec[l * DIM_C + t * 16 + col];
      #pragma unroll
      for (int r = 0; r < 4; ++r) {
        float v = c[t][r] + bt;
        v = (v >= 0.f) ? v : 0.2f * v;
        c[t][r] = v;
        sq[r] += v * v;
      }
    }
    #pragma unroll
    for (int r = 0; r < 4; ++r) {
      #pragma unroll
      for (int m = 1; m < 16; m <<= 1) sq[r] += __shfl_xor(sq[r], m);
      sq[r] = 1.0f / fmaxf(sqrtf(sq[r]), 1e-12f);
    }
    #pragma unroll
    for (int t = 0; t < 4; ++t) {
      #pragma unroll
      for (int r = 0; r < 4; ++r) {
        const int node = nb + q * 4 + r;
        out[1 + (size_t)node * 256 + (size_t)(l + 1) * 64 + t * 16 + col] =
            c[t][r] * sq[r];
      }
    }
  }

  for (int idx = lane; idx < 16 * DIM_C; idx += 64) {
    const int node = nb + (idx >> 6);
    const int cc = idx & 63;
    float e = (node < N_USERS_C)
                  ? user_emb[(size_t)node * DIM_C + cc]
                  : item_emb[(size_t)(node - N_USERS_C) * DIM_C + cc];
    out[1 + (size_t)node * 256 + cc] = e;
  }
}

// ---------------------------------------------------------------------------
// Loss: one wave per batch element; block-level LDS reduction; per-block
// partials to ws (NO global atomics). part[b] = mf, part[LOSS_NB+b] = reg.
// ---------------------------------------------------------------------------
__global__ __launch_bounds__(256) void loss_kernel(
    const float* __restrict__ out, const int* __restrict__ bu,
    const int* __restrict__ bp, const int* __restrict__ bn,
    float* __restrict__ part) {
  __shared__ float smf[4];
  __shared__ float srg[4];
  const int wave = threadIdx.x >> 6;
  const int lane = threadIdx.x & 63;
  const int j = blockIdx.x * 4 + wave;

  const float* urow = out + 1 + (size_t)bu[j] * 256;
  const float* prow = out + 1 + ((size_t)N_USERS_C + bp[j]) * 256;
  const float* nrow = out + 1 + ((size_t)N_USERS_C + bn[j]) * 256;

  float4 u = ((const float4*)urow)[lane];
  float4 pp = ((const float4*)prow)[lane];
  float4 nn = ((const float4*)nrow)[lane];

  float x = u.x * (pp.x - nn.x) + u.y * (pp.y - nn.y) +
            u.z * (pp.z - nn.z) + u.w * (pp.w - nn.w);
  float r = u.x * u.x + u.y * u.y + u.z * u.z + u.w * u.w +
            pp.x * pp.x + pp.y * pp.y + pp.z * pp.z + pp.w * pp.w +
            nn.x * nn.x + nn.y * nn.y + nn.z * nn.z + nn.w * nn.w;

  #pragma unroll
  for (int o = 32; o; o >>= 1) {
    x += __shfl_xor(x, o);
    r += __shfl_xor(r, o);
  }
  if (lane == 0) {
    float ls = fminf(x, 0.f) - log1pf(expf(-fabsf(x)));
    smf[wave] = -ls;
    srg[wave] = 0.5f * r;
  }
  __syncthreads();
  if (threadIdx.x == 0) {
    part[blockIdx.x] = smf[0] + smf[1] + smf[2] + smf[3];
    part[LOSS_NB + blockIdx.x] = srg[0] + srg[1] + srg[2] + srg[3];
  }
}

// ---------------------------------------------------------------------------
// Finalize: single block reduces 2x1024 partials -> out[0]
// ---------------------------------------------------------------------------
__global__ __launch_bounds__(256) void finalize_kernel(
    const float* __restrict__ part, float* __restrict__ out) {
  __shared__ float smf[4];
  __shared__ float srg[4];
  const int tid = threadIdx.x;
  float mf = 0.f, rg = 0.f;
  #pragma unroll
  for (int k = 0; k < LOSS_NB / 256; ++k) {
    mf += part[tid + k * 256];
    rg += part[LOSS_NB + tid + k * 256];
  }
  #pragma unroll
  for (int o = 32; o; o >>= 1) {
    mf += __shfl_xor(mf, o);
    rg += __shfl_xor(rg, o);
  }
  if ((tid & 63) == 0) {
    smf[tid >> 6] = mf;
    srg[tid >> 6] = rg;
  }
  __syncthreads();
  if (tid == 0) {
    float m = smf[0] + smf[1] + smf[2] + smf[3];
    float g = srg[0] + srg[1] + srg[2] + srg[3];
    out[0] = m / (float)BATCH_C + DECAY_C * g / (float)BATCH_C;
  }
}

// ---------------------------------------------------------------------------
extern "C" void kernel_launch(void* const* d_in, const int* in_sizes, int n_in,
                              void* d_out, int out_size, void* d_ws, size_t ws_size,
                              hipStream_t stream) {
  const float* user_emb = (const float*)d_in[0];
  const float* item_emb = (const float*)d_in[1];
  const float* edge_val = (const float*)d_in[2];
  const float* W        = (const float*)d_in[3];
  const float* bvec     = (const float*)d_in[4];
  const int* edge_row   = (const int*)d_in[5];
  const int* edge_col   = (const int*)d_in[6];
  const int* bu         = (const int*)d_in[7];
  const int* bp         = (const int*)d_in[8];
  const int* bn         = (const int*)d_in[9];

  float* out = (float*)d_out;
  int* ws = (int*)d_ws;
  int* off         = ws + WS_OFF;
  int* bcnt        = ws + WS_BCNT;
  int* bucketStart = ws + WS_BSTART;
  int* cursB1      = ws + WS_CB1;
  uint4* wfrag     = (uint4*)(ws + WS_WFRAG);
  float* part      = (float*)(ws + WS_PART);
  unsigned* entP   = (unsigned*)(ws + WS_ENT);
  ushort* bf16tab  = (ushort*)(ws + WS_BF16);
  int2* ent1       = (int2*)(out + ENT1_FLOAT_OFF);

  hipMemsetAsync(bcnt, 0, NBUCK * sizeof(int), stream);

  cast_kernel<<<(2400000 + 255) / 256, 256, 0, stream>>>(user_emb, item_emb,
                                                         bf16tab);
  wprep_kernel<<<6, 256, 0, stream>>>(W, wfrag);
  bucket_hist_kernel<<<NTILES, 256, 0, stream>>>(edge_row, edge_col, bcnt);
  scan512_kernel<<<1, 512, 0, stream>>>(bcnt, bucketStart, cursB1);
  part1_kernel<<<NTILES, 256, 0, stream>>>(edge_row, edge_col, edge_val,
                                           cursB1, ent1);
  part2_kernel<<<NBUCK, 256, 0, stream>>>(bucketStart, ent1, off, entP);
  gather_kernel<<<2048, 256, 0, stream>>>(bf16tab, off, entP, out);
  transform_kernel<<<(N_NODES_C + 63) / 64, 256, 0, stream>>>(
      user_emb, item_emb, wfrag, bvec, out);
  loss_kernel<<<LOSS_NB, 256, 0, stream>>>(out, bu, bp, bn, part);
  finalize_kernel<<<1, 256, 0, stream>>>(part, out);
}

// Round 11
// 285.921 us; speedup vs baseline: 2.5889x; 1.0017x over previous
//
#include <hip/hip_runtime.h>
#include <math.h>

#define N_USERS_C 100000
#define N_ITEMS_C 50000
#define N_NODES_C 150000
#define N_EDGES_C 2000000
#define N_ENTRIES_C 4000000
#define DIM_C 64
#define DECAY_C 1e-4f
#define BATCH_C 4096

#define TILE_EDGES 2048
#define NTILES ((N_EDGES_C + TILE_EDGES - 1) / TILE_EDGES)   // 977

// 512 entry-balanced buckets: 256 user buckets x 391 nodes, 256 item x 196.
#define UB_NODES 391
#define IB_NODES 196
#define NBUCK 512
#define B1_DEPTH 14

#define LOSS_NB (BATCH_C / 4)  // 1024 blocks, 4 batch elems (waves) each

// ws layout (4-byte units):
//   off[150032] | bcnt[512] | bucketStart[520] | cursB1[512] | acc[24] |
//   wfrag[6144] | part[2048] | entP[4M ints] | bf16 tables (4.8M ints)
#define WS_OFF 0
#define WS_BCNT 150032
#define WS_BSTART 150544
#define WS_CB1 151064
#define WS_ACC 151576
#define WS_WFRAG 151600
#define WS_PART 157744
#define WS_ENT 159792
#define WS_BF16 4159792
// total 8,959,792 ints = 35.84 MB

// ent1 staging (8B entries, f32 val) in d_out tail, consumed by part2
// before gather/transform overwrite that region (stream-ordered).
#define ENT1_FLOAT_OFF 30400000

typedef __attribute__((ext_vector_type(8))) short short8v;
typedef __attribute__((ext_vector_type(4))) float f32x4;

__device__ __forceinline__ unsigned bf16_bits(float v) {
  unsigned u = __float_as_uint(v);
  return (u + 0x8000u) >> 16;
}

__device__ __forceinline__ short8v as_short8(uint4 u) {
  union { uint4 u4; short8v s8; } x;
  x.u4 = u;
  return x.s8;
}

// ---------------------------------------------------------------------------
// Kernel 0: cast both tables to bf16 (user table then item table, contiguous)
// ---------------------------------------------------------------------------
__global__ __launch_bounds__(256) void cast_kernel(
    const float* __restrict__ user_emb, const float* __restrict__ item_emb,
    ushort* __restrict__ h) {
  const int t = blockIdx.x * 256 + threadIdx.x;  // one float4 per thread
  const int nUser4 = N_USERS_C * DIM_C / 4;
  const int nTot4 = (N_USERS_C + N_ITEMS_C) * DIM_C / 4;
  if (t >= nTot4) return;
  float4 v = (t < nUser4) ? ((const float4*)user_emb)[t]
                          : ((const float4*)item_emb)[t - nUser4];
  ushort4 o;
  o.x = (ushort)bf16_bits(v.x);
  o.y = (ushort)bf16_bits(v.y);
  o.z = (ushort)bf16_bits(v.z);
  o.w = (ushort)bf16_bits(v.w);
  *(ushort4*)&h[(size_t)t * 4] = o;
}

// ---------------------------------------------------------------------------
// Kernel 0b: pack W into 24 MFMA B-fragments (bf16).
// ---------------------------------------------------------------------------
__global__ __launch_bounds__(256) void wprep_kernel(
    const float* __restrict__ W, uint4* __restrict__ wfrag) {
  const int g = blockIdx.x * 256 + threadIdx.x;
  if (g >= 24 * 64) return;
  const int f = g >> 6, l = g & 63;
  const int layer = f >> 3, rem = f & 7, t = rem >> 1, s = rem & 1;
  const int n = t * 16 + (l & 15);
  const int k0 = s * 32 + (l >> 4) * 8;
  const float* base = W + layer * DIM_C * DIM_C + n;  // stride 64 per k
  unsigned r[4];
  #pragma unroll
  for (int j = 0; j < 4; ++j) {
    unsigned lo = bf16_bits(base[(size_t)(k0 + 2 * j) * DIM_C]);
    unsigned hi = bf16_bits(base[(size_t)(k0 + 2 * j + 1) * DIM_C]);
    r[j] = lo | (hi << 16);
  }
  wfrag[g] = make_uint4(r[0], r[1], r[2], r[3]);
}

// ---------------------------------------------------------------------------
// Kernel 1: bucket-level histogram (512 bins, LDS-aggregated)
// ---------------------------------------------------------------------------
__global__ __launch_bounds__(256) void bucket_hist_kernel(
    const int* __restrict__ edge_row, const int* __restrict__ edge_col,
    int* __restrict__ bcnt) {
  __shared__ int h[NBUCK];
  const int tid = threadIdx.x;
  for (int i = tid; i < NBUCK; i += 256) h[i] = 0;
  __syncthreads();
  const int base = blockIdx.x * TILE_EDGES;
  #pragma unroll
  for (int k = 0; k < 8; ++k) {
    int e = base + k * 256 + tid;
    if (e < N_EDGES_C) {
      atomicAdd(&h[(int)((unsigned)edge_row[e] / UB_NODES)], 1);
      atomicAdd(&h[256 + (int)((unsigned)edge_col[e] / IB_NODES)], 1);
    }
  }
  __syncthreads();
  for (int i = tid; i < NBUCK; i += 256) {
    int v = h[i];
    if (v) atomicAdd(&bcnt[i], v);
  }
}

// ---------------------------------------------------------------------------
// Kernel 2: exclusive scan of 512 bucket counts (single block)
// ---------------------------------------------------------------------------
__global__ __launch_bounds__(512) void scan512_kernel(
    const int* __restrict__ bcnt, int* __restrict__ bucketStart,
    int* __restrict__ cursB1) {
  __shared__ int ts[512];
  const int t = threadIdx.x;
  int c = bcnt[t];
  ts[t] = c;
  __syncthreads();
  #pragma unroll
  for (int o = 1; o < 512; o <<= 1) {
    int y = (t >= o) ? ts[t - o] : 0;
    __syncthreads();
    ts[t] += y;
    __syncthreads();
  }
  int excl = ts[t] - c;
  bucketStart[t] = excl;
  cursB1[t] = excl;
  if (t == 511) bucketStart[512] = ts[511];
}

// ---------------------------------------------------------------------------
// Phase B1: bin entries into 512 buckets (LDS staging + chunked flush).
// ---------------------------------------------------------------------------
__global__ __launch_bounds__(256) void part1_kernel(
    const int* __restrict__ edge_row, const int* __restrict__ edge_col,
    const float* __restrict__ edge_val, int* __restrict__ cursB1,
    int2* __restrict__ ent1) {
  __shared__ int2 stg[NBUCK][B1_DEPTH];  // 56 KB
  __shared__ int scnt[NBUCK];
  const int tid = threadIdx.x;
  for (int i = tid; i < NBUCK; i += 256) scnt[i] = 0;
  __syncthreads();

  const int base = blockIdx.x * TILE_EDGES;
  #pragma unroll
  for (int k = 0; k < 8; ++k) {
    int e = base + k * 256 + tid;
    if (e < N_EDGES_C) {
      int r = edge_row[e];
      int c = edge_col[e];
      int vb = __float_as_int(edge_val[e]);
      int ub = (int)((unsigned)r / UB_NODES);
      int2 E1 = make_int2(c | ((r - ub * UB_NODES) << 17), vb);
      int s1 = atomicAdd(&scnt[ub], 1);
      if (s1 < B1_DEPTH) stg[ub][s1] = E1;
      else ent1[atomicAdd(&cursB1[ub], 1)] = E1;
      int ib = (int)((unsigned)c / IB_NODES);
      int2 E2 = make_int2(r | ((c - ib * IB_NODES) << 17), vb);
      ib += 256;
      int s2 = atomicAdd(&scnt[ib], 1);
      if (s2 < B1_DEPTH) stg[ib][s2] = E2;
      else ent1[atomicAdd(&cursB1[ib], 1)] = E2;
    }
  }
  __syncthreads();
  for (int i = tid; i < NBUCK; i += 256) {
    int cn = scnt[i];
    if (cn > B1_DEPTH) cn = B1_DEPTH;
    if (cn) {
      int p = atomicAdd(&cursB1[i], cn);
      for (int j = 0; j < cn; ++j) ent1[p + j] = stg[i][j];
    }
  }
}

// ---------------------------------------------------------------------------
// Phase B2: per-bucket local node histogram + LDS scan -> writes off[]
// coalesced, then scatters packed 4B entries via LDS cursor atomics.
// ---------------------------------------------------------------------------
__global__ __launch_bounds__(256) void part2_kernel(
    const int* __restrict__ bucketStart, const int2* __restrict__ ent1,
    int* __restrict__ off, unsigned* __restrict__ entP) {
  __shared__ int lhist[512];
  __shared__ int lexcl[512];
  __shared__ int ps[256];
  const int b = blockIdx.x;
  const int tid = threadIdx.x;
  int nb, nodes;
  if (b < 256) {
    nb = b * UB_NODES;
    int e = (b + 1) * UB_NODES;
    if (e > N_USERS_C) e = N_USERS_C;
    nodes = e - nb;
  } else {
    nb = N_USERS_C + (b - 256) * IB_NODES;
    int e = N_USERS_C + (b - 255) * IB_NODES;
    if (e > N_NODES_C) e = N_NODES_C;
    nodes = e - nb;
  }
  const int start = bucketStart[b];
  const int end = bucketStart[b + 1];

  for (int i = tid; i < 512; i += 256) lhist[i] = 0;
  __syncthreads();

  for (int i = start + tid; i < end; i += 256)
    atomicAdd(&lhist[(unsigned)ent1[i].x >> 17], 1);
  __syncthreads();

  int a0 = lhist[2 * tid];
  int a1 = lhist[2 * tid + 1];
  ps[tid] = a0 + a1;
  __syncthreads();
  #pragma unroll
  for (int o = 1; o < 256; o <<= 1) {
    int y = (tid >= o) ? ps[tid - o] : 0;
    __syncthreads();
    ps[tid] += y;
    __syncthreads();
  }
  int e0 = ps[tid] - a0 - a1;
  lexcl[2 * tid] = e0;
  lexcl[2 * tid + 1] = e0 + a0;
  __syncthreads();

  for (int t = tid; t < nodes; t += 256) off[nb + t] = start + lexcl[t];
  if (b == NBUCK - 1 && tid == 0) off[N_NODES_C] = N_ENTRIES_C;

  for (int i = tid; i < 512; i += 256) lhist[i] = lexcl[i];
  __syncthreads();

  const bool isUser = (b < 256);
  for (int i = start + tid; i < end; i += 256) {
    int2 E = ent1[i];
    int local = (int)((unsigned)E.x >> 17);
    int src = E.x & 0x1FFFF;
    unsigned hb = bf16_bits(__int_as_float(E.y));
    unsigned P;
    if (isUser) {
      P = (hb << 16) | (unsigned)src;
    } else {
      P = (((hb & 0xFFFEu) | ((unsigned)src & 1u)) << 16) |
          ((unsigned)src >> 1);
    }
    int p = start + atomicAdd(&lhist[local], 1);
    entP[p] = P;
  }
}

// ---------------------------------------------------------------------------
// Gather v2: octet-wave. Each 8-lane octet owns one entry (8 lanes x 16B
// uint4 = one 128B row) -> 8 entries concurrently per wave, 2-deep unroll
// -> 16 rows in flight. Cross-octet reduce: shfl_xor 8/16/32. Lanes 0..7
// write the bf16 agg row (same layout as before) into the ego slot.
// ---------------------------------------------------------------------------
__device__ __forceinline__ void acc_row8(float* __restrict__ a, unsigned E,
                                         bool isUser,
                                         const ushort* __restrict__ tblU,
                                         const ushort* __restrict__ tblI,
                                         int ol) {
  unsigned src;
  float v;
  const ushort* t;
  if (isUser) {  // uniform branch per node
    src = E & 0xFFFFu;
    v = __uint_as_float(E & 0xFFFF0000u);
    t = tblI;
  } else {
    src = ((E & 0xFFFFu) << 1) | ((E >> 16) & 1u);
    v = __uint_as_float(E & 0xFFFE0000u);
    t = tblU;
  }
  uint4 q = *(const uint4*)(t + ((size_t)src << 6) + (ol << 3));
  a[0] += v * __uint_as_float(q.x << 16);
  a[1] += v * __uint_as_float(q.x & 0xFFFF0000u);
  a[2] += v * __uint_as_float(q.y << 16);
  a[3] += v * __uint_as_float(q.y & 0xFFFF0000u);
  a[4] += v * __uint_as_float(q.z << 16);
  a[5] += v * __uint_as_float(q.z & 0xFFFF0000u);
  a[6] += v * __uint_as_float(q.w << 16);
  a[7] += v * __uint_as_float(q.w & 0xFFFF0000u);
}

__global__ __launch_bounds__(256) void gather_kernel(
    const ushort* __restrict__ bf16tab, const int* __restrict__ off,
    const unsigned* __restrict__ entP, float* __restrict__ out) {
  const int lane = threadIdx.x & 63;
  const int og = lane >> 3;   // octet 0..7 (one entry each)
  const int ol = lane & 7;    // lane in octet: 16B slice of the row
  const int wave0 = (blockIdx.x * 256 + threadIdx.x) >> 6;
  const int nWaves = gridDim.x * 4;
  const ushort* tblU = bf16tab;
  const ushort* tblI = bf16tab + (size_t)N_USERS_C * DIM_C;

  for (int n = wave0; n < N_NODES_C; n += nWaves) {
    const bool isUser = (n < N_USERS_C);
    int i = off[n] + og;
    const int end = off[n + 1];
    float a[8] = {0.f, 0.f, 0.f, 0.f, 0.f, 0.f, 0.f, 0.f};
    for (; i + 8 < end; i += 16) {  // 2 entries per octet in flight
      unsigned E0 = entP[i];
      unsigned E1 = entP[i + 8];
      acc_row8(a, E0, isUser, tblU, tblI, ol);
      acc_row8(a, E1, isUser, tblU, tblI, ol);
    }
    if (i < end) acc_row8(a, entP[i], isUser, tblU, tblI, ol);

    #pragma unroll
    for (int k = 0; k < 8; ++k) {
      a[k] += __shfl_xor(a[k], 8);
      a[k] += __shfl_xor(a[k], 16);
      a[k] += __shfl_xor(a[k], 32);
    }
    if (lane < 8) {  // og == 0: write cols [ol*8, ol*8+8) as bf16
      uint4 o;
      o.x = bf16_bits(a[0]) | (bf16_bits(a[1]) << 16);
      o.y = bf16_bits(a[2]) | (bf16_bits(a[3]) << 16);
      o.z = bf16_bits(a[4]) | (bf16_bits(a[5]) << 16);
      o.w = bf16_bits(a[6]) | (bf16_bits(a[7]) << 16);
      ((uint4*)(out + 4 + (size_t)n * 256))[ol] = o;
    }
  }
}

// ---------------------------------------------------------------------------
// Transform v3 (MFMA): wave = 16 nodes. 24 MFMA + in-register epilogue.
// ---------------------------------------------------------------------------
__global__ __launch_bounds__(256) void transform_kernel(
    const float* __restrict__ user_emb, const float* __restrict__ item_emb,
    const uint4* __restrict__ wfragG, const float* __restrict__ bvec,
    float* __restrict__ out) {
  __shared__ uint4 Wf[24 * 64];  // 24 KB
  const int tid = threadIdx.x;
  for (int i = tid; i < 24 * 64; i += 256) Wf[i] = wfragG[i];
  __syncthreads();

  const int wave = tid >> 6;
  const int lane = tid & 63;
  const int nb = blockIdx.x * 64 + wave * 16;
  if (nb >= N_NODES_C) return;  // whole-wave guard (150000 % 16 == 0)
  const int q = lane >> 4;
  const int col = lane & 15;

  const uint4* aggp = (const uint4*)(out + 4 + (size_t)(nb + col) * 256);
  short8v A0 = as_short8(aggp[q]);
  short8v A1 = as_short8(aggp[q + 4]);

  for (int l = 0; l < 3; ++l) {
    f32x4 c[4];
    #pragma unroll
    for (int t = 0; t < 4; ++t) c[t] = (f32x4){0.f, 0.f, 0.f, 0.f};
    const uint4* wl = &Wf[l * 8 * 64];
    #pragma unroll
    for (int t = 0; t < 4; ++t) {
      c[t] = __builtin_amdgcn_mfma_f32_16x16x32_bf16(
          A0, as_short8(wl[(t * 2 + 0) * 64 + lane]), c[t], 0, 0, 0);
      c[t] = __builtin_amdgcn_mfma_f32_16x16x32_bf16(
          A1, as_short8(wl[(t * 2 + 1) * 64 + lane]), c[t], 0, 0, 0);
    }

    float sq[4] = {0.f, 0.f, 0.f, 0.f};
    #pragma unroll
    for (int t = 0; t < 4; ++t) {
      const float bt = bvec[l * DIM_C + t * 16 + col];
      #pragma unroll
      for (int r = 0; r < 4; ++r) {
        float v = c[t][r] + bt;
        v = (v >= 0.f) ? v : 0.2f * v;
        c[t][r] = v;
        sq[r] += v * v;
      }
    }
    #pragma unroll
    for (int r = 0; r < 4; ++r) {
      #pragma unroll
      for (int m = 1; m < 16; m <<= 1) sq[r] += __shfl_xor(sq[r], m);
      sq[r] = 1.0f / fmaxf(sqrtf(sq[r]), 1e-12f);
    }
    #pragma unroll
    for (int t = 0; t < 4; ++t) {
      #pragma unroll
      for (int r = 0; r < 4; ++r) {
        const int node = nb + q * 4 + r;
        out[1 + (size_t)node * 256 + (size_t)(l + 1) * 64 + t * 16 + col] =
            c[t][r] * sq[r];
      }
    }
  }

  for (int idx = lane; idx < 16 * DIM_C; idx += 64) {
    const int node = nb + (idx >> 6);
    const int cc = idx & 63;
    float e = (node < N_USERS_C)
                  ? user_emb[(size_t)node * DIM_C + cc]
                  : item_emb[(size_t)(node - N_USERS_C) * DIM_C + cc];
    out[1 + (size_t)node * 256 + cc] = e;
  }
}

// ---------------------------------------------------------------------------
// Loss: one wave per batch element; block-level LDS reduction; per-block
// partials to ws (NO global atomics). part[b] = mf, part[LOSS_NB+b] = reg.
// ---------------------------------------------------------------------------
__global__ __launch_bounds__(256) void loss_kernel(
    const float* __restrict__ out, const int* __restrict__ bu,
    const int* __restrict__ bp, const int* __restrict__ bn,
    float* __restrict__ part) {
  __shared__ float smf[4];
  __shared__ float srg[4];
  const int wave = threadIdx.x >> 6;
  const int lane = threadIdx.x & 63;
  const int j = blockIdx.x * 4 + wave;

  const float* urow = out + 1 + (size_t)bu[j] * 256;
  const float* prow = out + 1 + ((size_t)N_USERS_C + bp[j]) * 256;
  const float* nrow = out + 1 + ((size_t)N_USERS_C + bn[j]) * 256;

  float4 u = ((const float4*)urow)[lane];
  float4 pp = ((const float4*)prow)[lane];
  float4 nn = ((const float4*)nrow)[lane];

  float x = u.x * (pp.x - nn.x) + u.y * (pp.y - nn.y) +
            u.z * (pp.z - nn.z) + u.w * (pp.w - nn.w);
  float r = u.x * u.x + u.y * u.y + u.z * u.z + u.w * u.w +
            pp.x * pp.x + pp.y * pp.y + pp.z * pp.z + pp.w * pp.w +
            nn.x * nn.x + nn.y * nn.y + nn.z * nn.z + nn.w * nn.w;

  #pragma unroll
  for (int o = 32; o; o >>= 1) {
    x += __shfl_xor(x, o);
    r += __shfl_xor(r, o);
  }
  if (lane == 0) {
    float ls = fminf(x, 0.f) - log1pf(expf(-fabsf(x)));
    smf[wave] = -ls;
    srg[wave] = 0.5f * r;
  }
  __syncthreads();
  if (threadIdx.x == 0) {
    part[blockIdx.x] = smf[0] + smf[1] + smf[2] + smf[3];
    part[LOSS_NB + blockIdx.x] = srg[0] + srg[1] + srg[2] + srg[3];
  }
}

// ---------------------------------------------------------------------------
// Finalize: single block reduces 2x1024 partials -> out[0]
// ---------------------------------------------------------------------------
__global__ __launch_bounds__(256) void finalize_kernel(
    const float* __restrict__ part, float* __restrict__ out) {
  __shared__ float smf[4];
  __shared__ float srg[4];
  const int tid = threadIdx.x;
  float mf = 0.f, rg = 0.f;
  #pragma unroll
  for (int k = 0; k < LOSS_NB / 256; ++k) {
    mf += part[tid + k * 256];
    rg += part[LOSS_NB + tid + k * 256];
  }
  #pragma unroll
  for (int o = 32; o; o >>= 1) {
    mf += __shfl_xor(mf, o);
    rg += __shfl_xor(rg, o);
  }
  if ((tid & 63) == 0) {
    smf[tid >> 6] = mf;
    srg[tid >> 6] = rg;
  }
  __syncthreads();
  if (tid == 0) {
    float m = smf[0] + smf[1] + smf[2] + smf[3];
    float g = srg[0] + srg[1] + srg[2] + srg[3];
    out[0] = m / (float)BATCH_C + DECAY_C * g / (float)BATCH_C;
  }
}

// ---------------------------------------------------------------------------
extern "C" void kernel_launch(void* const* d_in, const int* in_sizes, int n_in,
                              void* d_out, int out_size, void* d_ws, size_t ws_size,
                              hipStream_t stream) {
  const float* user_emb = (const float*)d_in[0];
  const float* item_emb = (const float*)d_in[1];
  const float* edge_val = (const float*)d_in[2];
  const float* W        = (const float*)d_in[3];
  const float* bvec     = (const float*)d_in[4];
  const int* edge_row   = (const int*)d_in[5];
  const int* edge_col   = (const int*)d_in[6];
  const int* bu         = (const int*)d_in[7];
  const int* bp         = (const int*)d_in[8];
  const int* bn         = (const int*)d_in[9];

  float* out = (float*)d_out;
  int* ws = (int*)d_ws;
  int* off         = ws + WS_OFF;
  int* bcnt        = ws + WS_BCNT;
  int* bucketStart = ws + WS_BSTART;
  int* cursB1      = ws + WS_CB1;
  uint4* wfrag     = (uint4*)(ws + WS_WFRAG);
  float* part      = (float*)(ws + WS_PART);
  unsigned* entP   = (unsigned*)(ws + WS_ENT);
  ushort* bf16tab  = (ushort*)(ws + WS_BF16);
  int2* ent1       = (int2*)(out + ENT1_FLOAT_OFF);

  hipMemsetAsync(bcnt, 0, NBUCK * sizeof(int), stream);

  cast_kernel<<<(2400000 + 255) / 256, 256, 0, stream>>>(user_emb, item_emb,
                                                         bf16tab);
  wprep_kernel<<<6, 256, 0, stream>>>(W, wfrag);
  bucket_hist_kernel<<<NTILES, 256, 0, stream>>>(edge_row, edge_col, bcnt);
  scan512_kernel<<<1, 512, 0, stream>>>(bcnt, bucketStart, cursB1);
  part1_kernel<<<NTILES, 256, 0, stream>>>(edge_row, edge_col, edge_val,
                                           cursB1, ent1);
  part2_kernel<<<NBUCK, 256, 0, stream>>>(bucketStart, ent1, off, entP);
  gather_kernel<<<2048, 256, 0, stream>>>(bf16tab, off, entP, out);
  transform_kernel<<<(N_NODES_C + 63) / 64, 256, 0, stream>>>(
      user_emb, item_emb, wfrag, bvec, out);
  loss_kernel<<<LOSS_NB, 256, 0, stream>>>(out, bu, bp, bn, part);
  finalize_kernel<<<1, 256, 0, stream>>>(part, out);
}